// Round 11
// baseline (586.659 us; speedup 1.0000x reference)
//
#include <hip/hip_runtime.h>
#include <hip/hip_bf16.h>
#include <math.h>

#define N_TX   100000
#define N_USER 50000
#define F_TX   128
#define F_USER 64
#define HID    64
#define NH     4
#define OUTC   32
#define NE     500000
#define HC1    256          // NH*HID
#define SLOPE  0.2f
#define NB_T   391          // (N_TX+255)/256
#define NB_U   196          // (N_USER+255)/256

__device__ __forceinline__ float elu_f(float x) { return x > 0.f ? x : (expf(x) - 1.f); }
// fast attention-weight exp: softmax normalizes away the ~1ulp v_exp error
__device__ __forceinline__ float lrelu_exp_fast(float x) { x = x > 0.f ? x : SLOPE * x; return __expf(x); }

// row-of-acc FMA: acc[i][0..3] += XS * WV.{x,y,z,w}  (named vars only -> register-resident)
#define ACC_STEP(i, XS, WV) \
    acc[i][0] = fmaf((XS), (WV).x, acc[i][0]); \
    acc[i][1] = fmaf((XS), (WV).y, acc[i][1]); \
    acc[i][2] = fmaf((XS), (WV).z, acc[i][2]); \
    acc[i][3] = fmaf((XS), (WV).w, acc[i][3]);
#define ACC4(i, XV) \
    ACC_STEP(i, (XV).x, w0) ACC_STEP(i, (XV).y, w1) \
    ACC_STEP(i, (XV).z, w2) ACC_STEP(i, (XV).w, w3)

// ---------------- tiled fp32 GEMM: C = act(A[N,K] @ B[K,M] + bias) ----------------
// Pad = 68 floats (272B, 16B-aligned) -> ds_read_b128 operands, conflict-free (r10: -40us).
__global__ __launch_bounds__(256) void gemm_kernel(const float* __restrict__ A,
    const float* __restrict__ B, const float* __restrict__ bias,
    float* __restrict__ C, int N, int K, int M, int act)
{
    __shared__ float As[16][68];
    __shared__ float Bs[16][68];
    const int tid = threadIdx.x;
    const int tx = tid % 16, ty = tid / 16;
    const int row0 = blockIdx.y * 64, col0 = blockIdx.x * 64;
    float acc[4][4] = {};
    for (int k0 = 0; k0 < K; k0 += 16) {
        #pragma unroll
        for (int i = 0; i < 4; ++i) {
            int idx = tid * 4 + i;           // 64x16 A tile
            int r = idx >> 4, kk = idx & 15;
            int gr = row0 + r;
            As[kk][r] = (gr < N) ? A[(size_t)gr * K + (k0 + kk)] : 0.f;
        }
        #pragma unroll
        for (int i = 0; i < 4; ++i) {
            int idx = tid * 4 + i;           // 16x64 B tile
            int kk = idx >> 6, c = idx & 63;
            int gc = col0 + c;
            Bs[kk][c] = (gc < M) ? B[(size_t)(k0 + kk) * M + gc] : 0.f;
        }
        __syncthreads();
        #pragma unroll 2
        for (int kk = 0; kk < 16; ++kk) {
            const float4 av = *(const float4*)(&As[kk][ty * 4]);
            const float4 bv = *(const float4*)(&Bs[kk][tx * 4]);
            ACC_STEP(0, av.x, bv)
            ACC_STEP(1, av.y, bv)
            ACC_STEP(2, av.z, bv)
            ACC_STEP(3, av.w, bv)
        }
        __syncthreads();
    }
    #pragma unroll
    for (int i = 0; i < 4; ++i) {
        int r = row0 + ty * 4 + i;
        if (r >= N) continue;
        #pragma unroll
        for (int j = 0; j < 4; ++j) {
            int c = col0 + tx * 4 + j;
            if (c >= M) continue;
            float v = acc[i][j] + (bias ? bias[c] : 0.f);
            if (act == 1) v = elu_f(v);
            C[(size_t)r * M + c] = v;
        }
    }
}

// ====== DUAL projection GEMM (tx + user in one launch) with fused ELU + attn epilogue ======
// blockIdx.y < NB1 -> tx params; else user params. M==64, grid.x==1 for both.
__global__ __launch_bounds__(256) void gemm_proj_attn_dual(
    const float* __restrict__ A1, const float* __restrict__ B1, const float* __restrict__ bias1,
    float* __restrict__ C1, int N1, int K1,
    const float* __restrict__ Ma1, float* __restrict__ oa1,
    const float* __restrict__ Mb1, float* __restrict__ ob1, int NB1,
    const float* __restrict__ A2, const float* __restrict__ B2, const float* __restrict__ bias2,
    float* __restrict__ C2, int N2, int K2,
    const float* __restrict__ Ma2, float* __restrict__ oa2,
    const float* __restrict__ Mb2, float* __restrict__ ob2)
{
    __shared__ float As[16][68];
    __shared__ float Bs[16][68];
    const int tid = threadIdx.x;
    const int tx = tid % 16, ty = tid / 16;
    const float* A; const float* B; const float* bias; float* C; int N, K;
    const float* Ma; float* oa; const float* Mb; float* ob; int row0;
    if ((int)blockIdx.y < NB1) {
        A = A1; B = B1; bias = bias1; C = C1; N = N1; K = K1;
        Ma = Ma1; oa = oa1; Mb = Mb1; ob = ob1;
        row0 = blockIdx.y * 64;
    } else {
        A = A2; B = B2; bias = bias2; C = C2; N = N2; K = K2;
        Ma = Ma2; oa = oa2; Mb = Mb2; ob = ob2;
        row0 = (blockIdx.y - NB1) * 64;
    }
    float acc[4][4] = {};
    for (int k0 = 0; k0 < K; k0 += 16) {
        #pragma unroll
        for (int i = 0; i < 4; ++i) {
            int idx = tid * 4 + i;           // 64x16 A tile
            int r = idx >> 4, kk = idx & 15;
            int gr = row0 + r;
            As[kk][r] = (gr < N) ? A[(size_t)gr * K + (k0 + kk)] : 0.f;
        }
        #pragma unroll
        for (int i = 0; i < 4; ++i) {
            int idx = tid * 4 + i;           // 16x64 B tile (M==64, no col guard)
            int kk = idx >> 6, c = idx & 63;
            Bs[kk][c] = B[(size_t)(k0 + kk) * 64 + c];
        }
        __syncthreads();
        #pragma unroll 2
        for (int kk = 0; kk < 16; ++kk) {
            const float4 av = *(const float4*)(&As[kk][ty * 4]);
            const float4 bv = *(const float4*)(&Bs[kk][tx * 4]);
            ACC_STEP(0, av.x, bv)
            ACC_STEP(1, av.y, bv)
            ACC_STEP(2, av.z, bv)
            ACC_STEP(3, av.w, bv)
        }
        __syncthreads();
    }
    // ---- epilogue: ELU + store row + fused dots against Ma/Mb ([c][4] layout) ----
    const float4 ma0 = *(const float4*)(Ma + (tx * 4 + 0) * 4);
    const float4 ma1 = *(const float4*)(Ma + (tx * 4 + 1) * 4);
    const float4 ma2 = *(const float4*)(Ma + (tx * 4 + 2) * 4);
    const float4 ma3 = *(const float4*)(Ma + (tx * 4 + 3) * 4);
    const float4 mb0 = *(const float4*)(Mb + (tx * 4 + 0) * 4);
    const float4 mb1 = *(const float4*)(Mb + (tx * 4 + 1) * 4);
    const float4 mb2 = *(const float4*)(Mb + (tx * 4 + 2) * 4);
    const float4 mb3 = *(const float4*)(Mb + (tx * 4 + 3) * 4);
    const float4 bb  = *(const float4*)(bias + tx * 4);
    #pragma unroll
    for (int i = 0; i < 4; ++i) {
        int r = row0 + ty * 4 + i;
        bool wr = (r < N);
        float v0 = acc[i][0] + bb.x; v0 = v0 > 0.f ? v0 : (expf(v0) - 1.f);
        float v1 = acc[i][1] + bb.y; v1 = v1 > 0.f ? v1 : (expf(v1) - 1.f);
        float v2 = acc[i][2] + bb.z; v2 = v2 > 0.f ? v2 : (expf(v2) - 1.f);
        float v3 = acc[i][3] + bb.w; v3 = v3 > 0.f ? v3 : (expf(v3) - 1.f);
        if (wr) *(float4*)(C + (size_t)r * 64 + tx * 4) = make_float4(v0, v1, v2, v3);
        float pax = v0 * ma0.x + v1 * ma1.x + v2 * ma2.x + v3 * ma3.x;
        float pay = v0 * ma0.y + v1 * ma1.y + v2 * ma2.y + v3 * ma3.y;
        float paz = v0 * ma0.z + v1 * ma1.z + v2 * ma2.z + v3 * ma3.z;
        float paw = v0 * ma0.w + v1 * ma1.w + v2 * ma2.w + v3 * ma3.w;
        float pbx = v0 * mb0.x + v1 * mb1.x + v2 * mb2.x + v3 * mb3.x;
        float pby = v0 * mb0.y + v1 * mb1.y + v2 * mb2.y + v3 * mb3.y;
        float pbz = v0 * mb0.z + v1 * mb1.z + v2 * mb2.z + v3 * mb3.z;
        float pbw = v0 * mb0.w + v1 * mb1.w + v2 * mb2.w + v3 * mb3.w;
        #pragma unroll
        for (int off = 1; off < 16; off <<= 1) {
            pax += __shfl_xor(pax, off); pay += __shfl_xor(pay, off);
            paz += __shfl_xor(paz, off); paw += __shfl_xor(paw, off);
            pbx += __shfl_xor(pbx, off); pby += __shfl_xor(pby, off);
            pbz += __shfl_xor(pbz, off); pbw += __shfl_xor(pbw, off);
        }
        if (tx == 0 && wr) {
            *(float4*)(oa + (size_t)r * 4) = make_float4(pax, pay, paz, paw);
            *(float4*)(ob + (size_t)r * 4) = make_float4(pbx, pby, pbz, pbw);
        }
    }
}

// ------------- fold attention vectors into weights: Mv[k,h] = sum_c W[k,h*C+c]*a[h,c] -------------
struct AVArgs  { const float* W; const float* a; float* out; int K; int H; int C; };
struct AVArgs6 { AVArgs t[6]; };

__global__ void attn_vecs_kernel(AVArgs6 args)
{
    AVArgs A = args.t[blockIdx.x];
    int tid = threadIdx.x;
    if (tid < A.K * A.H) {
        int k = tid % A.K, h = tid / A.K;
        float s = 0.f;
        const float* wrow = A.W + (size_t)k * (A.H * A.C) + h * A.C;
        const float* arow = A.a + h * A.C;
        for (int c = 0; c < A.C; ++c) s += wrow[c] * arow[c];
        A.out[k * A.H + h] = s;
    }
}

// ================= merged CSR build (both edge types per launch) =================
__global__ __launch_bounds__(256) void hist2_kernel(const int* __restrict__ dst_t,
    const int* __restrict__ dst_u, int* __restrict__ deg_t, int* __restrict__ deg_u)
{
    int e = blockIdx.x * 256 + threadIdx.x;
    if (e < NE) atomicAdd(&deg_t[dst_t[e]], 1);
    else {
        e -= NE;
        if (e < NE) atomicAdd(&deg_u[dst_u[e]], 1);
    }
}

__global__ __launch_bounds__(256) void block_sum2_kernel(const int* __restrict__ deg_t,
    int* __restrict__ bsum_t, const int* __restrict__ deg_u, int* __restrict__ bsum_u)
{
    __shared__ int lds[256];
    int b = blockIdx.x, t = threadIdx.x;
    const int* deg; int* bsum; int Nd, lb;
    if (b < NB_T) { deg = deg_t; bsum = bsum_t; Nd = N_TX; lb = b; }
    else         { deg = deg_u; bsum = bsum_u; Nd = N_USER; lb = b - NB_T; }
    int i = lb * 256 + t;
    lds[t] = (i < Nd) ? deg[i] : 0;
    __syncthreads();
    for (int o = 128; o > 0; o >>= 1) {
        if (t < o) lds[t] += lds[t + o];
        __syncthreads();
    }
    if (t == 0) bsum[lb] = lds[0];
}

__global__ __launch_bounds__(512) void scan_bsum2_kernel(int* __restrict__ bt,
    int* __restrict__ bu)
{
    __shared__ int lds[512];
    int t = threadIdx.x;
    {
        int v = (t < NB_T) ? bt[t] : 0;
        lds[t] = v;
        __syncthreads();
        for (int o = 1; o < 512; o <<= 1) {
            int x = (t >= o) ? lds[t - o] : 0;
            __syncthreads();
            lds[t] += x;
            __syncthreads();
        }
        if (t < NB_T) bt[t] = lds[t] - v;
        __syncthreads();
    }
    {
        int v = (t < NB_U) ? bu[t] : 0;
        lds[t] = v;
        __syncthreads();
        for (int o = 1; o < 512; o <<= 1) {
            int x = (t >= o) ? lds[t - o] : 0;
            __syncthreads();
            lds[t] += x;
            __syncthreads();
        }
        if (t < NB_U) bu[t] = lds[t] - v;
    }
}

__global__ __launch_bounds__(256) void scan_final2_kernel(
    const int* __restrict__ deg_t, const int* __restrict__ be_t,
    int* __restrict__ rowptr_t, int* __restrict__ cur_t,
    const int* __restrict__ deg_u, const int* __restrict__ be_u,
    int* __restrict__ rowptr_u, int* __restrict__ cur_u)
{
    __shared__ int lds[256];
    int b = blockIdx.x, t = threadIdx.x;
    const int* deg; const int* be; int* rowptr; int* cursor; int Nd, lb;
    if (b < NB_T) { deg = deg_t; be = be_t; rowptr = rowptr_t; cursor = cur_t; Nd = N_TX; lb = b; }
    else         { deg = deg_u; be = be_u; rowptr = rowptr_u; cursor = cur_u; Nd = N_USER; lb = b - NB_T; }
    int i = lb * 256 + t;
    int v = (i < Nd) ? deg[i] : 0;
    lds[t] = v;
    __syncthreads();
    for (int o = 1; o < 256; o <<= 1) {
        int x = (t >= o) ? lds[t - o] : 0;
        __syncthreads();
        lds[t] += x;
        __syncthreads();
    }
    int excl = lds[t] - v + be[lb];
    if (i < Nd) {
        rowptr[i] = excl;
        cursor[i] = excl;
        if (i == Nd - 1) rowptr[Nd] = NE;
    }
}

// ---- scatter + edge-weight precompute: one thread per edge, full 64-lane parallelism ----
__global__ __launch_bounds__(256) void scatter2_ew_kernel(
    const int* __restrict__ src_t, const int* __restrict__ dst_t,
    int* __restrict__ cur_t, int* __restrict__ csr_t, float* __restrict__ ew_t,
    const float* __restrict__ als_t, const float* __restrict__ ald_t,
    const int* __restrict__ src_u, const int* __restrict__ dst_u,
    int* __restrict__ cur_u, int* __restrict__ csr_u, float* __restrict__ ew_u,
    const float* __restrict__ als_u, const float* __restrict__ ald_u)
{
    int e = blockIdx.x * 256 + threadIdx.x;
    const int* srcA; const int* dstA; int* cur; int* csr; float* ew;
    const float* als; const float* ald;
    if (e < NE) {
        srcA = src_t; dstA = dst_t; cur = cur_t; csr = csr_t; ew = ew_t;
        als = als_t; ald = ald_t;
    } else {
        e -= NE;
        if (e >= NE) return;
        srcA = src_u; dstA = dst_u; cur = cur_u; csr = csr_u; ew = ew_u;
        als = als_u; ald = ald_u;
    }
    int s = srcA[e], d = dstA[e];
    int p = atomicAdd(&cur[d], 1);
    csr[p] = s;
    float4 a = *(const float4*)(als + (size_t)s * 4);
    float4 b = *(const float4*)(ald + (size_t)d * 4);
    float4 w;
    w.x = lrelu_exp_fast(a.x + b.x);
    w.y = lrelu_exp_fast(a.y + b.y);
    w.z = lrelu_exp_fast(a.z + b.z);
    w.w = lrelu_exp_fast(a.w + b.w);
    *(float4*)(ew + (size_t)p * 4) = w;
}

// ================= conv1 aggregation: one wave per dst node, precomputed weights ==========
__device__ __forceinline__ void acc_edge(int s, int i, int lane,
    const float* __restrict__ ew, const float* __restrict__ hsrc,
    float& a0, float& a1, float& a2, float& a3,
    float& w0, float& w1, float& w2, float& w3)
{
    float4 e = *(const float4*)(ew + (size_t)i * 4);   // streaming broadcast
    float x = hsrc[(size_t)s * 64 + lane];             // 256B gather
    a0 = fmaf(e.x, x, a0); w0 += e.x;
    a1 = fmaf(e.y, x, a1); w1 += e.y;
    a2 = fmaf(e.z, x, a2); w2 += e.z;
    a3 = fmaf(e.w, x, a3); w3 += e.w;
}

__global__ __launch_bounds__(256) void agg_conv1_kernel(const int* __restrict__ rowptr,
    const int* __restrict__ csr, const float* __restrict__ hsrc,
    const float* __restrict__ ew, float* __restrict__ agg, int Nd)
{
    int d = blockIdx.x * 4 + (threadIdx.x >> 6);
    int lane = threadIdx.x & 63;
    if (d >= Nd) return;
    int beg = rowptr[d], end = rowptr[d + 1];
    float a0 = 0.f, a1 = 0.f, a2 = 0.f, a3 = 0.f;
    float w0 = 0.f, w1 = 0.f, w2 = 0.f, w3 = 0.f;
    int i = beg;
    for (; i + 2 <= end; i += 2) {
        int s0 = csr[i], s1 = csr[i + 1];
        acc_edge(s0, i,     lane, ew, hsrc, a0, a1, a2, a3, w0, w1, w2, w3);
        acc_edge(s1, i + 1, lane, ew, hsrc, a0, a1, a2, a3, w0, w1, w2, w3);
    }
    if (i < end)
        acc_edge(csr[i], i, lane, ew, hsrc, a0, a1, a2, a3, w0, w1, w2, w3);
    float* o = agg + (size_t)d * 256;
    o[lane]       = a0 / (w0 + 1e-16f);
    o[64 + lane]  = a1 / (w1 + 1e-16f);
    o[128 + lane] = a2 / (w2 + 1e-16f);
    o[192 + lane] = a3 / (w3 + 1e-16f);
}

// ================= conv1 dst-side transform v9: no sX staging, direct global x ============
// v6 staged x to LDS, but each x element is consumed ONCE per head-block (reuse is only
// across the 16-lane tx broadcast, which global-load coalescing handles natively). v9:
// k-loop reads x straight from global (4 broadcast dwordx4/chunk = 4x 64B lines/wave-instr,
// same traffic) -> LDS halves to sW-only (16.4KB), staging VALU+barrier gone, occupancy
// 4 -> ~8 blocks/CU hides the global latency. __syncthreads before epilogue keeps the
// in-place u1 write safe (all x reads drained; head-blocks write disjoint col-slices).
// `#pragma unroll 1` load-bearing as ever (r1/r2 scratch-spill lesson).
__global__ __launch_bounds__(256) void transform_v9(
    const float* __restrict__ agg, const float* __restrict__ W1,
    const float* __restrict__ b1, const float* __restrict__ vvec,
    float* __restrict__ dot_part, float* __restrict__ rows_out,
    int Nd, int writeRows)
{
    __shared__ float sW[64 * 64];             // [c][col]
    const int tid  = threadIdx.x;
    const int h    = blockIdx.y;
    const int base = blockIdx.x * 64;

    // ---- stage W head-slice: row c, cols h*64..h*64+63 ----
    #pragma unroll
    for (int it = 0; it < 4; ++it) {
        int c    = it * 16 + (tid >> 4);
        int col0 = (tid & 15) * 4;
        *(float4*)(sW + c * 64 + col0) =
            *(const float4*)(W1 + (size_t)c * 256 + h * 64 + col0);
    }
    __syncthreads();

    const int tx = tid & 15;                  // col group (4 cols)
    const int ty = tid >> 4;                  // node group (4 nodes)
    const int r0 = base + ty * 4;
    // OOB rows clamp to a valid address; their results are discarded in the epilogue.
    const float* xr0 = agg + (size_t)(r0 + 0 < Nd ? r0 + 0 : Nd - 1) * 256 + h * 64;
    const float* xr1 = agg + (size_t)(r0 + 1 < Nd ? r0 + 1 : Nd - 1) * 256 + h * 64;
    const float* xr2 = agg + (size_t)(r0 + 2 < Nd ? r0 + 2 : Nd - 1) * 256 + h * 64;
    const float* xr3 = agg + (size_t)(r0 + 3 < Nd ? r0 + 3 : Nd - 1) * 256 + h * 64;
    float acc[4][4] = {};

    #pragma unroll 1
    for (int c0 = 0; c0 < 64; c0 += 4) {
        const float4 x0 = *(const float4*)(xr0 + c0);
        const float4 x1 = *(const float4*)(xr1 + c0);
        const float4 x2 = *(const float4*)(xr2 + c0);
        const float4 x3 = *(const float4*)(xr3 + c0);
        const float4 w0 = *(const float4*)(sW + (c0 + 0) * 64 + tx * 4);
        const float4 w1 = *(const float4*)(sW + (c0 + 1) * 64 + tx * 4);
        const float4 w2 = *(const float4*)(sW + (c0 + 2) * 64 + tx * 4);
        const float4 w3 = *(const float4*)(sW + (c0 + 3) * 64 + tx * 4);
        ACC4(0, x0)
        ACC4(1, x1)
        ACC4(2, x2)
        ACC4(3, x3)
    }
    __syncthreads();   // in-place (u1): all x reads complete before any epilogue write

    // ---- epilogue: bias + ELU, optional row write, vvec dot-partials ----
    const float4 bb = *(const float4*)(b1   + h * 64 + tx * 4);
    const float4 vv = *(const float4*)(vvec + h * 64 + tx * 4);
    float* dp = dot_part + (size_t)h * Nd;
    #pragma unroll
    for (int i = 0; i < 4; ++i) {
        int g = base + ty * 4 + i;            // uniform across the 16-lane tx group
        if (g >= Nd) continue;
        float v0 = acc[i][0] + bb.x; v0 = v0 > 0.f ? v0 : (expf(v0) - 1.f);
        float v1 = acc[i][1] + bb.y; v1 = v1 > 0.f ? v1 : (expf(v1) - 1.f);
        float v2 = acc[i][2] + bb.z; v2 = v2 > 0.f ? v2 : (expf(v2) - 1.f);
        float v3 = acc[i][3] + bb.w; v3 = v3 > 0.f ? v3 : (expf(v3) - 1.f);
        if (writeRows)
            *(float4*)(rows_out + (size_t)g * 256 + h * 64 + tx * 4) =
                make_float4(v0, v1, v2, v3);
        float s = v0 * vv.x + v1 * vv.y + v2 * vv.z + v3 * vv.w;
        s += __shfl_xor(s, 1); s += __shfl_xor(s, 2);
        s += __shfl_xor(s, 4); s += __shfl_xor(s, 8);
        if (tx == 0) dp[g] = s;
    }
}

// ------------- sum 4 head partials: o1[i] = sum_h ap[h*N1+i]; o2 likewise -------------
__global__ __launch_bounds__(256) void combine_parts(
    const float* __restrict__ ap, float* __restrict__ o1, int N1,
    const float* __restrict__ bp, float* __restrict__ o2, int N2)
{
    int i = blockIdx.x * 256 + threadIdx.x;
    if (i < N1) {
        o1[i] = ap[i] + ap[N1 + i] + ap[2 * N1 + i] + ap[3 * N1 + i];
    } else {
        int j = i - N1;
        if (j < N2)
            o2[j] = bp[j] + bp[N2 + j] + bp[2 * N2 + j] + bp[3 * N2 + j];
    }
}

// ================= conv2: fused edge-softmax + aggregation + bias/ELU + classifier ==========
__global__ __launch_bounds__(256) void conv2_fused_kernel(const int* __restrict__ rowptr,
    const int* __restrict__ csr, const float* __restrict__ hs2,
    const float* __restrict__ als2, const float* __restrict__ ald2,
    const float* __restrict__ b2, const float* __restrict__ Wc, const float* __restrict__ bc,
    float* __restrict__ out, int Nd)
{
    int d = blockIdx.x * 4 + (threadIdx.x >> 6);
    int lane = threadIdx.x & 63;
    if (d >= Nd) return;
    int beg = rowptr[d], end = rowptr[d + 1];
    float aldd = ald2[d];
    int half = lane >> 5, c = lane & 31;
    float acc = 0.f, wsum = 0.f;
    for (int i = beg + half; i < end; i += 2) {
        int s = csr[i];
        float w = lrelu_exp_fast(als2[s] + aldd);
        acc = fmaf(w, hs2[(size_t)s * 32 + c], acc);
        wsum += w;
    }
    acc  += __shfl_down(acc, 32);
    wsum += __shfl_down(wsum, 32);
    float val = 0.f;
    if (lane < 32) {
        float t2 = acc / (wsum + 1e-16f) + b2[c];
        t2 = t2 > 0.f ? t2 : (expf(t2) - 1.f);
        val = t2 * Wc[c];
    }
    #pragma unroll
    for (int o = 16; o > 0; o >>= 1) val += __shfl_down(val, o);
    if (lane == 0) out[d] = val + bc[0];
}

extern "C" void kernel_launch(void* const* d_in, const int* in_sizes, int n_in,
                              void* d_out, int out_size, void* d_ws, size_t ws_size,
                              hipStream_t stream)
{
    const float* x_tx    = (const float*)d_in[0];
    const float* x_user  = (const float*)d_in[1];
    const int*   ei_u2t  = (const int*)d_in[2];
    const int*   ei_t2u  = (const int*)d_in[3];
    const float* Wp_tx   = (const float*)d_in[4];
    const float* bp_tx   = (const float*)d_in[5];
    const float* Wp_user = (const float*)d_in[6];
    const float* bp_user = (const float*)d_in[7];
    const float* W1_u2t  = (const float*)d_in[8];
    const float* as1_u2t = (const float*)d_in[9];
    const float* ad1_u2t = (const float*)d_in[10];
    const float* b1_u2t  = (const float*)d_in[11];
    const float* W2_u2t  = (const float*)d_in[12];
    const float* as2_u2t = (const float*)d_in[13];
    const float* ad2_u2t = (const float*)d_in[14];
    const float* b2_u2t  = (const float*)d_in[15];
    const float* W1_t2u  = (const float*)d_in[16];
    const float* as1_t2u = (const float*)d_in[17];
    const float* ad1_t2u = (const float*)d_in[18];
    const float* b1_t2u  = (const float*)d_in[19];
    const float* Wc      = (const float*)d_in[24];
    const float* bc      = (const float*)d_in[25];
    float* out = (float*)d_out;
    float* ws  = (float*)d_ws;

    const int* src_u2t = ei_u2t;            // user ids
    const int* dst_u2t = ei_u2t + NE;       // tx ids
    const int* src_t2u = ei_t2u;            // tx ids
    const int* dst_u   = ei_t2u + NE;       // user ids

    // ---- workspace layout (floats) ----
    float* h_tx   = ws;                     //  6,400,000
    float* h_us   = ws + 6400000;           //  3,200,000
    float* hs2    = ws + 9600000;           //  1,600,000  (ald2p/als2p alias here pre-gemm)
    float* als2   = ws + 11200000;          //     50,000
    float* ald2   = ws + 11250000;          //    100,000
    float* als_us = ws + 11350000;          //    200,000  (user src-attn for u2t)
    float* ald_us = ws + 11550000;          //    200,000  (user dst-attn for t2u)
    float* als_tx = ws + 11750000;          //    400,000  (tx src-attn for t2u)
    float* ald_tx = ws + 12150000;          //    400,000  (tx dst-attn for u2t)
    float* agg    = ws + 12550000;          // 25,600,000  (u2t then t2u; u1 in place)
    float* avec   = ws + 38150000;          //      1,536
    float* ald2p = hs2;                     //    400,000  (4 x N_TX, aliases hs2)
    float* als2p = hs2 + 400000;            //    200,000  (4 x N_USER)
    float* ew_t   = ws + 38152000;          //  2,000,000  (4 x NE, csr-order weights u2t)
    float* ew_u   = ws + 40152000;          //  2,000,000  (4 x NE, csr-order weights t2u)
    // ---- int region ----
    int* ibase    = (int*)(ws + 42152000);
    int* deg_t    = ibase;                  //   100,000
    int* deg_u    = ibase + 100000;         //    50,000
    int* rowptr_t = ibase + 150000;         //   100,001
    int* cur_t    = ibase + 250001;         //   100,000
    int* csr_t    = ibase + 350001;         //   500,000
    int* rowptr_u = ibase + 850001;         //    50,001
    int* cur_u    = ibase + 900002;         //    50,000
    int* csr_u    = ibase + 950002;         //   500,000
    int* bsum_t   = ibase + 1450002;        //       512
    int* bsum_u   = ibase + 1450514;        //       512

    float* Msrc_u2t = avec + 0;
    float* Mdst_u2t = avec + 256;
    float* Msrc_t2u = avec + 512;
    float* Mdst_t2u = avec + 768;
    float* vsrc2    = avec + 1024;          // fold(W2, as2): als2 = u1 . vsrc2
    float* vdst2    = avec + 1280;          // fold(W2, ad2): ald2 = t1 . vdst2

    // ---- fold attention vectors into weights ----
    AVArgs6 av;
    av.t[0] = { W1_u2t, as1_u2t, Msrc_u2t, HID, NH, HID };
    av.t[1] = { W1_u2t, ad1_u2t, Mdst_u2t, HID, NH, HID };
    av.t[2] = { W1_t2u, as1_t2u, Msrc_t2u, HID, NH, HID };
    av.t[3] = { W1_t2u, ad1_t2u, Mdst_t2u, HID, NH, HID };
    av.t[4] = { W2_u2t, as2_u2t, vsrc2, HC1, 1, OUTC };
    av.t[5] = { W2_u2t, ad2_u2t, vdst2, HC1, 1, OUTC };
    attn_vecs_kernel<<<6, 256, 0, stream>>>(av);

    // ---- zero degree histograms ----
    hipMemsetAsync(deg_t, 0, 150000 * sizeof(int), stream);

    // ---- CSR histogram + prefix scans (no scatter yet) ----
    hist2_kernel<<<(2 * NE + 255) / 256, 256, 0, stream>>>(dst_u2t, dst_u, deg_t, deg_u);
    block_sum2_kernel<<<NB_T + NB_U, 256, 0, stream>>>(deg_t, bsum_t, deg_u, bsum_u);
    scan_bsum2_kernel<<<1, 512, 0, stream>>>(bsum_t, bsum_u);
    scan_final2_kernel<<<NB_T + NB_U, 256, 0, stream>>>(
        deg_t, bsum_t, rowptr_t, cur_t, deg_u, bsum_u, rowptr_u, cur_u);

    // ---- input projections (both node types, ONE launch) with fused attn epilogue ----
    const int NB1 = (N_TX + 63) / 64;
    const int NB2 = (N_USER + 63) / 64;
    gemm_proj_attn_dual<<<dim3(1, NB1 + NB2), 256, 0, stream>>>(
        x_tx, Wp_tx, bp_tx, h_tx, N_TX, F_TX,
        Mdst_u2t, ald_tx, Msrc_t2u, als_tx, NB1,
        x_user, Wp_user, bp_user, h_us, N_USER, F_USER,
        Msrc_u2t, als_us, Mdst_t2u, ald_us);

    // ---- scatter + edge-weight precompute (both edge types) ----
    scatter2_ew_kernel<<<(2 * NE + 255) / 256, 256, 0, stream>>>(
        src_u2t, dst_u2t, cur_t, csr_t, ew_t, als_us, ald_tx,
        src_t2u, dst_u,   cur_u, csr_u, ew_u, als_tx, ald_us);

    // ================= conv1, u2t (dst = tx): agg -> transform -> ald2 partials ==========
    agg_conv1_kernel<<<(N_TX + 3) / 4, 256, 0, stream>>>(
        rowptr_t, csr_t, h_us, ew_t, agg, N_TX);
    transform_v9<<<dim3((N_TX + 63) / 64, NH), 256, 0, stream>>>(
        agg, W1_u2t, b1_u2t, vdst2, ald2p, nullptr, N_TX, 0);

    // ================= conv1, t2u (dst = user): agg -> transform (u1 in place) ==========
    agg_conv1_kernel<<<(N_USER + 3) / 4, 256, 0, stream>>>(
        rowptr_u, csr_u, h_tx, ew_u, agg, N_USER);
    transform_v9<<<dim3((N_USER + 63) / 64, NH), 256, 0, stream>>>(
        agg, W1_t2u, b1_t2u, vsrc2, als2p, agg, N_USER, 1);
    float* u1 = agg;

    // ---- combine head partials ----
    combine_parts<<<(N_TX + N_USER + 255) / 256, 256, 0, stream>>>(
        ald2p, ald2, N_TX, als2p, als2, N_USER);

    // ================= conv2 projection + fused conv2/classifier =================
    gemm_kernel<<<dim3(1, (N_USER + 63) / 64), 256, 0, stream>>>(
        u1, W2_u2t, nullptr, hs2, N_USER, HC1, OUTC, 0);
    conv2_fused_kernel<<<(N_TX + 3) / 4, 256, 0, stream>>>(
        rowptr_t, csr_t, hs2, als2, ald2, b2_u2t, Wc, bc, out, N_TX);
}

// Round 12
// 585.899 us; speedup vs baseline: 1.0013x; 1.0013x over previous
//
#include <hip/hip_runtime.h>
#include <hip/hip_bf16.h>
#include <math.h>

#define N_TX   100000
#define N_USER 50000
#define F_TX   128
#define F_USER 64
#define HID    64
#define NH     4
#define OUTC   32
#define NE     500000
#define HC1    256          // NH*HID
#define SLOPE  0.2f
#define NB_T   391          // (N_TX+255)/256
#define NB_U   196          // (N_USER+255)/256

__device__ __forceinline__ float elu_f(float x) { return x > 0.f ? x : (expf(x) - 1.f); }
// fast attention-weight exp: softmax normalizes away the ~1ulp v_exp error
__device__ __forceinline__ float lrelu_exp_fast(float x) { x = x > 0.f ? x : SLOPE * x; return __expf(x); }

// row-of-acc FMA: acc[i][0..3] += XS * WV.{x,y,z,w}  (named vars only -> register-resident)
#define ACC_STEP(i, XS, WV) \
    acc[i][0] = fmaf((XS), (WV).x, acc[i][0]); \
    acc[i][1] = fmaf((XS), (WV).y, acc[i][1]); \
    acc[i][2] = fmaf((XS), (WV).z, acc[i][2]); \
    acc[i][3] = fmaf((XS), (WV).w, acc[i][3]);
#define ACC4(i, XV) \
    ACC_STEP(i, (XV).x, w0) ACC_STEP(i, (XV).y, w1) \
    ACC_STEP(i, (XV).z, w2) ACC_STEP(i, (XV).w, w3)

// ---------------- tiled fp32 GEMM: C = act(A[N,K] @ B[K,M] + bias) ----------------
// Pad = 68 floats (272B, 16B-aligned) -> ds_read_b128 operands, conflict-free (r10: -40us).
__global__ __launch_bounds__(256) void gemm_kernel(const float* __restrict__ A,
    const float* __restrict__ B, const float* __restrict__ bias,
    float* __restrict__ C, int N, int K, int M, int act)
{
    __shared__ float As[16][68];
    __shared__ float Bs[16][68];
    const int tid = threadIdx.x;
    const int tx = tid % 16, ty = tid / 16;
    const int row0 = blockIdx.y * 64, col0 = blockIdx.x * 64;
    float acc[4][4] = {};
    for (int k0 = 0; k0 < K; k0 += 16) {
        #pragma unroll
        for (int i = 0; i < 4; ++i) {
            int idx = tid * 4 + i;           // 64x16 A tile
            int r = idx >> 4, kk = idx & 15;
            int gr = row0 + r;
            As[kk][r] = (gr < N) ? A[(size_t)gr * K + (k0 + kk)] : 0.f;
        }
        #pragma unroll
        for (int i = 0; i < 4; ++i) {
            int idx = tid * 4 + i;           // 16x64 B tile
            int kk = idx >> 6, c = idx & 63;
            int gc = col0 + c;
            Bs[kk][c] = (gc < M) ? B[(size_t)(k0 + kk) * M + gc] : 0.f;
        }
        __syncthreads();
        #pragma unroll 2
        for (int kk = 0; kk < 16; ++kk) {
            const float4 av = *(const float4*)(&As[kk][ty * 4]);
            const float4 bv = *(const float4*)(&Bs[kk][tx * 4]);
            ACC_STEP(0, av.x, bv)
            ACC_STEP(1, av.y, bv)
            ACC_STEP(2, av.z, bv)
            ACC_STEP(3, av.w, bv)
        }
        __syncthreads();
    }
    #pragma unroll
    for (int i = 0; i < 4; ++i) {
        int r = row0 + ty * 4 + i;
        if (r >= N) continue;
        #pragma unroll
        for (int j = 0; j < 4; ++j) {
            int c = col0 + tx * 4 + j;
            if (c >= M) continue;
            float v = acc[i][j] + (bias ? bias[c] : 0.f);
            if (act == 1) v = elu_f(v);
            C[(size_t)r * M + c] = v;
        }
    }
}

// ====== DUAL projection GEMM (tx + user in one launch) with fused ELU + attn epilogue ======
// blockIdx.y < NB1 -> tx params; else user params. M==64, grid.x==1 for both.
__global__ __launch_bounds__(256) void gemm_proj_attn_dual(
    const float* __restrict__ A1, const float* __restrict__ B1, const float* __restrict__ bias1,
    float* __restrict__ C1, int N1, int K1,
    const float* __restrict__ Ma1, float* __restrict__ oa1,
    const float* __restrict__ Mb1, float* __restrict__ ob1, int NB1,
    const float* __restrict__ A2, const float* __restrict__ B2, const float* __restrict__ bias2,
    float* __restrict__ C2, int N2, int K2,
    const float* __restrict__ Ma2, float* __restrict__ oa2,
    const float* __restrict__ Mb2, float* __restrict__ ob2)
{
    __shared__ float As[16][68];
    __shared__ float Bs[16][68];
    const int tid = threadIdx.x;
    const int tx = tid % 16, ty = tid / 16;
    const float* A; const float* B; const float* bias; float* C; int N, K;
    const float* Ma; float* oa; const float* Mb; float* ob; int row0;
    if ((int)blockIdx.y < NB1) {
        A = A1; B = B1; bias = bias1; C = C1; N = N1; K = K1;
        Ma = Ma1; oa = oa1; Mb = Mb1; ob = ob1;
        row0 = blockIdx.y * 64;
    } else {
        A = A2; B = B2; bias = bias2; C = C2; N = N2; K = K2;
        Ma = Ma2; oa = oa2; Mb = Mb2; ob = ob2;
        row0 = (blockIdx.y - NB1) * 64;
    }
    float acc[4][4] = {};
    for (int k0 = 0; k0 < K; k0 += 16) {
        #pragma unroll
        for (int i = 0; i < 4; ++i) {
            int idx = tid * 4 + i;           // 64x16 A tile
            int r = idx >> 4, kk = idx & 15;
            int gr = row0 + r;
            As[kk][r] = (gr < N) ? A[(size_t)gr * K + (k0 + kk)] : 0.f;
        }
        #pragma unroll
        for (int i = 0; i < 4; ++i) {
            int idx = tid * 4 + i;           // 16x64 B tile (M==64, no col guard)
            int kk = idx >> 6, c = idx & 63;
            Bs[kk][c] = B[(size_t)(k0 + kk) * 64 + c];
        }
        __syncthreads();
        #pragma unroll 2
        for (int kk = 0; kk < 16; ++kk) {
            const float4 av = *(const float4*)(&As[kk][ty * 4]);
            const float4 bv = *(const float4*)(&Bs[kk][tx * 4]);
            ACC_STEP(0, av.x, bv)
            ACC_STEP(1, av.y, bv)
            ACC_STEP(2, av.z, bv)
            ACC_STEP(3, av.w, bv)
        }
        __syncthreads();
    }
    // ---- epilogue: ELU + store row + fused dots against Ma/Mb ([c][4] layout) ----
    const float4 ma0 = *(const float4*)(Ma + (tx * 4 + 0) * 4);
    const float4 ma1 = *(const float4*)(Ma + (tx * 4 + 1) * 4);
    const float4 ma2 = *(const float4*)(Ma + (tx * 4 + 2) * 4);
    const float4 ma3 = *(const float4*)(Ma + (tx * 4 + 3) * 4);
    const float4 mb0 = *(const float4*)(Mb + (tx * 4 + 0) * 4);
    const float4 mb1 = *(const float4*)(Mb + (tx * 4 + 1) * 4);
    const float4 mb2 = *(const float4*)(Mb + (tx * 4 + 2) * 4);
    const float4 mb3 = *(const float4*)(Mb + (tx * 4 + 3) * 4);
    const float4 bb  = *(const float4*)(bias + tx * 4);
    #pragma unroll
    for (int i = 0; i < 4; ++i) {
        int r = row0 + ty * 4 + i;
        bool wr = (r < N);
        float v0 = acc[i][0] + bb.x; v0 = v0 > 0.f ? v0 : (expf(v0) - 1.f);
        float v1 = acc[i][1] + bb.y; v1 = v1 > 0.f ? v1 : (expf(v1) - 1.f);
        float v2 = acc[i][2] + bb.z; v2 = v2 > 0.f ? v2 : (expf(v2) - 1.f);
        float v3 = acc[i][3] + bb.w; v3 = v3 > 0.f ? v3 : (expf(v3) - 1.f);
        if (wr) *(float4*)(C + (size_t)r * 64 + tx * 4) = make_float4(v0, v1, v2, v3);
        float pax = v0 * ma0.x + v1 * ma1.x + v2 * ma2.x + v3 * ma3.x;
        float pay = v0 * ma0.y + v1 * ma1.y + v2 * ma2.y + v3 * ma3.y;
        float paz = v0 * ma0.z + v1 * ma1.z + v2 * ma2.z + v3 * ma3.z;
        float paw = v0 * ma0.w + v1 * ma1.w + v2 * ma2.w + v3 * ma3.w;
        float pbx = v0 * mb0.x + v1 * mb1.x + v2 * mb2.x + v3 * mb3.x;
        float pby = v0 * mb0.y + v1 * mb1.y + v2 * mb2.y + v3 * mb3.y;
        float pbz = v0 * mb0.z + v1 * mb1.z + v2 * mb2.z + v3 * mb3.z;
        float pbw = v0 * mb0.w + v1 * mb1.w + v2 * mb2.w + v3 * mb3.w;
        #pragma unroll
        for (int off = 1; off < 16; off <<= 1) {
            pax += __shfl_xor(pax, off); pay += __shfl_xor(pay, off);
            paz += __shfl_xor(paz, off); paw += __shfl_xor(paw, off);
            pbx += __shfl_xor(pbx, off); pby += __shfl_xor(pby, off);
            pbz += __shfl_xor(pbz, off); pbw += __shfl_xor(pbw, off);
        }
        if (tx == 0 && wr) {
            *(float4*)(oa + (size_t)r * 4) = make_float4(pax, pay, paz, paw);
            *(float4*)(ob + (size_t)r * 4) = make_float4(pbx, pby, pbz, pbw);
        }
    }
}

// ------------- fold attention vectors into weights: Mv[k,h] = sum_c W[k,h*C+c]*a[h,c] -------------
struct AVArgs  { const float* W; const float* a; float* out; int K; int H; int C; };
struct AVArgs6 { AVArgs t[6]; };

__global__ void attn_vecs_kernel(AVArgs6 args)
{
    AVArgs A = args.t[blockIdx.x];
    int tid = threadIdx.x;
    if (tid < A.K * A.H) {
        int k = tid % A.K, h = tid / A.K;
        float s = 0.f;
        const float* wrow = A.W + (size_t)k * (A.H * A.C) + h * A.C;
        const float* arow = A.a + h * A.C;
        for (int c = 0; c < A.C; ++c) s += wrow[c] * arow[c];
        A.out[k * A.H + h] = s;
    }
}

// ================= merged CSR build (both edge types per launch) =================
__global__ __launch_bounds__(256) void hist2_kernel(const int* __restrict__ dst_t,
    const int* __restrict__ dst_u, int* __restrict__ deg_t, int* __restrict__ deg_u)
{
    int e = blockIdx.x * 256 + threadIdx.x;
    if (e < NE) atomicAdd(&deg_t[dst_t[e]], 1);
    else {
        e -= NE;
        if (e < NE) atomicAdd(&deg_u[dst_u[e]], 1);
    }
}

__global__ __launch_bounds__(256) void block_sum2_kernel(const int* __restrict__ deg_t,
    int* __restrict__ bsum_t, const int* __restrict__ deg_u, int* __restrict__ bsum_u)
{
    __shared__ int lds[256];
    int b = blockIdx.x, t = threadIdx.x;
    const int* deg; int* bsum; int Nd, lb;
    if (b < NB_T) { deg = deg_t; bsum = bsum_t; Nd = N_TX; lb = b; }
    else         { deg = deg_u; bsum = bsum_u; Nd = N_USER; lb = b - NB_T; }
    int i = lb * 256 + t;
    lds[t] = (i < Nd) ? deg[i] : 0;
    __syncthreads();
    for (int o = 128; o > 0; o >>= 1) {
        if (t < o) lds[t] += lds[t + o];
        __syncthreads();
    }
    if (t == 0) bsum[lb] = lds[0];
}

__global__ __launch_bounds__(512) void scan_bsum2_kernel(int* __restrict__ bt,
    int* __restrict__ bu)
{
    __shared__ int lds[512];
    int t = threadIdx.x;
    {
        int v = (t < NB_T) ? bt[t] : 0;
        lds[t] = v;
        __syncthreads();
        for (int o = 1; o < 512; o <<= 1) {
            int x = (t >= o) ? lds[t - o] : 0;
            __syncthreads();
            lds[t] += x;
            __syncthreads();
        }
        if (t < NB_T) bt[t] = lds[t] - v;
        __syncthreads();
    }
    {
        int v = (t < NB_U) ? bu[t] : 0;
        lds[t] = v;
        __syncthreads();
        for (int o = 1; o < 512; o <<= 1) {
            int x = (t >= o) ? lds[t - o] : 0;
            __syncthreads();
            lds[t] += x;
            __syncthreads();
        }
        if (t < NB_U) bu[t] = lds[t] - v;
    }
}

__global__ __launch_bounds__(256) void scan_final2_kernel(
    const int* __restrict__ deg_t, const int* __restrict__ be_t,
    int* __restrict__ rowptr_t, int* __restrict__ cur_t,
    const int* __restrict__ deg_u, const int* __restrict__ be_u,
    int* __restrict__ rowptr_u, int* __restrict__ cur_u)
{
    __shared__ int lds[256];
    int b = blockIdx.x, t = threadIdx.x;
    const int* deg; const int* be; int* rowptr; int* cursor; int Nd, lb;
    if (b < NB_T) { deg = deg_t; be = be_t; rowptr = rowptr_t; cursor = cur_t; Nd = N_TX; lb = b; }
    else         { deg = deg_u; be = be_u; rowptr = rowptr_u; cursor = cur_u; Nd = N_USER; lb = b - NB_T; }
    int i = lb * 256 + t;
    int v = (i < Nd) ? deg[i] : 0;
    lds[t] = v;
    __syncthreads();
    for (int o = 1; o < 256; o <<= 1) {
        int x = (t >= o) ? lds[t - o] : 0;
        __syncthreads();
        lds[t] += x;
        __syncthreads();
    }
    int excl = lds[t] - v + be[lb];
    if (i < Nd) {
        rowptr[i] = excl;
        cursor[i] = excl;
        if (i == Nd - 1) rowptr[Nd] = NE;
    }
}

// ---- scatter + edge-weight precompute: one thread per edge, full 64-lane parallelism ----
__global__ __launch_bounds__(256) void scatter2_ew_kernel(
    const int* __restrict__ src_t, const int* __restrict__ dst_t,
    int* __restrict__ cur_t, int* __restrict__ csr_t, float* __restrict__ ew_t,
    const float* __restrict__ als_t, const float* __restrict__ ald_t,
    const int* __restrict__ src_u, const int* __restrict__ dst_u,
    int* __restrict__ cur_u, int* __restrict__ csr_u, float* __restrict__ ew_u,
    const float* __restrict__ als_u, const float* __restrict__ ald_u)
{
    int e = blockIdx.x * 256 + threadIdx.x;
    const int* srcA; const int* dstA; int* cur; int* csr; float* ew;
    const float* als; const float* ald;
    if (e < NE) {
        srcA = src_t; dstA = dst_t; cur = cur_t; csr = csr_t; ew = ew_t;
        als = als_t; ald = ald_t;
    } else {
        e -= NE;
        if (e >= NE) return;
        srcA = src_u; dstA = dst_u; cur = cur_u; csr = csr_u; ew = ew_u;
        als = als_u; ald = ald_u;
    }
    int s = srcA[e], d = dstA[e];
    int p = atomicAdd(&cur[d], 1);
    csr[p] = s;
    float4 a = *(const float4*)(als + (size_t)s * 4);
    float4 b = *(const float4*)(ald + (size_t)d * 4);
    float4 w;
    w.x = lrelu_exp_fast(a.x + b.x);
    w.y = lrelu_exp_fast(a.y + b.y);
    w.z = lrelu_exp_fast(a.z + b.z);
    w.w = lrelu_exp_fast(a.w + b.w);
    *(float4*)(ew + (size_t)p * 4) = w;
}

// ================= conv1 aggregation: one wave per dst node, precomputed weights ==========
__device__ __forceinline__ void acc_edge(int s, int i, int lane,
    const float* __restrict__ ew, const float* __restrict__ hsrc,
    float& a0, float& a1, float& a2, float& a3,
    float& w0, float& w1, float& w2, float& w3)
{
    float4 e = *(const float4*)(ew + (size_t)i * 4);   // streaming broadcast
    float x = hsrc[(size_t)s * 64 + lane];             // 256B gather
    a0 = fmaf(e.x, x, a0); w0 += e.x;
    a1 = fmaf(e.y, x, a1); w1 += e.y;
    a2 = fmaf(e.z, x, a2); w2 += e.z;
    a3 = fmaf(e.w, x, a3); w3 += e.w;
}

__global__ __launch_bounds__(256) void agg_conv1_kernel(const int* __restrict__ rowptr,
    const int* __restrict__ csr, const float* __restrict__ hsrc,
    const float* __restrict__ ew, float* __restrict__ agg, int Nd)
{
    int d = blockIdx.x * 4 + (threadIdx.x >> 6);
    int lane = threadIdx.x & 63;
    if (d >= Nd) return;
    int beg = rowptr[d], end = rowptr[d + 1];
    float a0 = 0.f, a1 = 0.f, a2 = 0.f, a3 = 0.f;
    float w0 = 0.f, w1 = 0.f, w2 = 0.f, w3 = 0.f;
    int i = beg;
    for (; i + 2 <= end; i += 2) {
        int s0 = csr[i], s1 = csr[i + 1];
        acc_edge(s0, i,     lane, ew, hsrc, a0, a1, a2, a3, w0, w1, w2, w3);
        acc_edge(s1, i + 1, lane, ew, hsrc, a0, a1, a2, a3, w0, w1, w2, w3);
    }
    if (i < end)
        acc_edge(csr[i], i, lane, ew, hsrc, a0, a1, a2, a3, w0, w1, w2, w3);
    float* o = agg + (size_t)d * 256;
    o[lane]       = a0 / (w0 + 1e-16f);
    o[64 + lane]  = a1 / (w1 + 1e-16f);
    o[128 + lane] = a2 / (w2 + 1e-16f);
    o[192 + lane] = a3 / (w3 + 1e-16f);
}

// ================= conv1 dst-side transform v6 (proven 67-69us): 64-node tile, 4x4/thread ==
// LDS-BW bound at ~1.5x the 46us LDS floor; v8 (bigger tile) lost to occupancy, v9
// (global-direct x) lost to L2 latency -> v6 is the optimum of this fp32 structure.
// `#pragma unroll 1` on the k-loop is load-bearing (r1/r2: full unroll -> cross-iteration
// ds_read hoisting past the VGPR budget -> deterministic 2.5 GB/launch scratch spill).
__global__ __launch_bounds__(256) void transform_v6(
    const float* __restrict__ agg, const float* __restrict__ W1,
    const float* __restrict__ b1, const float* __restrict__ vvec,
    float* __restrict__ dot_part, float* __restrict__ rows_out,
    int Nd, int writeRows)
{
    constexpr int SXP = 68;                   // row stride (floats): 272B, 16B-aligned
    __shared__ float sX[64 * SXP];            // [node][c]
    __shared__ float sW[64 * 64];             // [c][col]
    const int tid  = threadIdx.x;
    const int w    = tid >> 6;
    const int lane = tid & 63;
    const int h    = blockIdx.y;
    const int base = blockIdx.x * 64;

    // ---- stage x tile: wave w stages node rows, 256B contiguous per row ----
    #pragma unroll
    for (int it = 0; it < 4; ++it) {
        int r  = w * 16 + it * 4 + (lane >> 4);
        int c0 = (lane & 15) * 4;
        int g  = base + r;
        float4 v = make_float4(0.f, 0.f, 0.f, 0.f);
        if (g < Nd) v = *(const float4*)(agg + (size_t)g * 256 + h * 64 + c0);
        *(float4*)(sX + r * SXP + c0) = v;
    }
    // ---- stage W head-slice: row c, cols h*64..h*64+63 ----
    #pragma unroll
    for (int it = 0; it < 4; ++it) {
        int c    = w * 16 + it * 4 + (lane >> 4);
        int col0 = (lane & 15) * 4;
        *(float4*)(sW + c * 64 + col0) =
            *(const float4*)(W1 + (size_t)c * 256 + h * 64 + col0);
    }
    __syncthreads();

    const int tx = tid & 15;                  // col group (4 cols)
    const int ty = tid >> 4;                  // node group (4 nodes)
    float acc[4][4] = {};

    #pragma unroll 1
    for (int c0 = 0; c0 < 64; c0 += 4) {
        const float4 x0 = *(const float4*)(sX + (ty * 4 + 0) * SXP + c0);
        const float4 x1 = *(const float4*)(sX + (ty * 4 + 1) * SXP + c0);
        const float4 x2 = *(const float4*)(sX + (ty * 4 + 2) * SXP + c0);
        const float4 x3 = *(const float4*)(sX + (ty * 4 + 3) * SXP + c0);
        const float4 w0 = *(const float4*)(sW + (c0 + 0) * 64 + tx * 4);
        const float4 w1 = *(const float4*)(sW + (c0 + 1) * 64 + tx * 4);
        const float4 w2 = *(const float4*)(sW + (c0 + 2) * 64 + tx * 4);
        const float4 w3 = *(const float4*)(sW + (c0 + 3) * 64 + tx * 4);
        ACC4(0, x0)
        ACC4(1, x1)
        ACC4(2, x2)
        ACC4(3, x3)
    }

    // ---- epilogue: bias + ELU, optional row write, vvec dot-partials ----
    const float4 bb = *(const float4*)(b1   + h * 64 + tx * 4);
    const float4 vv = *(const float4*)(vvec + h * 64 + tx * 4);
    float* dp = dot_part + (size_t)h * Nd;
    #pragma unroll
    for (int i = 0; i < 4; ++i) {
        int g = base + ty * 4 + i;            // uniform across the 16-lane tx group
        if (g >= Nd) continue;
        float v0 = acc[i][0] + bb.x; v0 = v0 > 0.f ? v0 : (expf(v0) - 1.f);
        float v1 = acc[i][1] + bb.y; v1 = v1 > 0.f ? v1 : (expf(v1) - 1.f);
        float v2 = acc[i][2] + bb.z; v2 = v2 > 0.f ? v2 : (expf(v2) - 1.f);
        float v3 = acc[i][3] + bb.w; v3 = v3 > 0.f ? v3 : (expf(v3) - 1.f);
        if (writeRows)
            *(float4*)(rows_out + (size_t)g * 256 + h * 64 + tx * 4) =
                make_float4(v0, v1, v2, v3);
        float s = v0 * vv.x + v1 * vv.y + v2 * vv.z + v3 * vv.w;
        s += __shfl_xor(s, 1); s += __shfl_xor(s, 2);
        s += __shfl_xor(s, 4); s += __shfl_xor(s, 8);
        if (tx == 0) dp[g] = s;
    }
}

// ------------- sum 4 head partials: o1[i] = sum_h ap[h*N1+i]; o2 likewise -------------
__global__ __launch_bounds__(256) void combine_parts(
    const float* __restrict__ ap, float* __restrict__ o1, int N1,
    const float* __restrict__ bp, float* __restrict__ o2, int N2)
{
    int i = blockIdx.x * 256 + threadIdx.x;
    if (i < N1) {
        o1[i] = ap[i] + ap[N1 + i] + ap[2 * N1 + i] + ap[3 * N1 + i];
    } else {
        int j = i - N1;
        if (j < N2)
            o2[j] = bp[j] + bp[N2 + j] + bp[2 * N2 + j] + bp[3 * N2 + j];
    }
}

// ================= conv2: fused edge-softmax + aggregation + bias/ELU + classifier ==========
__global__ __launch_bounds__(256) void conv2_fused_kernel(const int* __restrict__ rowptr,
    const int* __restrict__ csr, const float* __restrict__ hs2,
    const float* __restrict__ als2, const float* __restrict__ ald2,
    const float* __restrict__ b2, const float* __restrict__ Wc, const float* __restrict__ bc,
    float* __restrict__ out, int Nd)
{
    int d = blockIdx.x * 4 + (threadIdx.x >> 6);
    int lane = threadIdx.x & 63;
    if (d >= Nd) return;
    int beg = rowptr[d], end = rowptr[d + 1];
    float aldd = ald2[d];
    int half = lane >> 5, c = lane & 31;
    float acc = 0.f, wsum = 0.f;
    for (int i = beg + half; i < end; i += 2) {
        int s = csr[i];
        float w = lrelu_exp_fast(als2[s] + aldd);
        acc = fmaf(w, hs2[(size_t)s * 32 + c], acc);
        wsum += w;
    }
    acc  += __shfl_down(acc, 32);
    wsum += __shfl_down(wsum, 32);
    float val = 0.f;
    if (lane < 32) {
        float t2 = acc / (wsum + 1e-16f) + b2[c];
        t2 = t2 > 0.f ? t2 : (expf(t2) - 1.f);
        val = t2 * Wc[c];
    }
    #pragma unroll
    for (int o = 16; o > 0; o >>= 1) val += __shfl_down(val, o);
    if (lane == 0) out[d] = val + bc[0];
}

extern "C" void kernel_launch(void* const* d_in, const int* in_sizes, int n_in,
                              void* d_out, int out_size, void* d_ws, size_t ws_size,
                              hipStream_t stream)
{
    const float* x_tx    = (const float*)d_in[0];
    const float* x_user  = (const float*)d_in[1];
    const int*   ei_u2t  = (const int*)d_in[2];
    const int*   ei_t2u  = (const int*)d_in[3];
    const float* Wp_tx   = (const float*)d_in[4];
    const float* bp_tx   = (const float*)d_in[5];
    const float* Wp_user = (const float*)d_in[6];
    const float* bp_user = (const float*)d_in[7];
    const float* W1_u2t  = (const float*)d_in[8];
    const float* as1_u2t = (const float*)d_in[9];
    const float* ad1_u2t = (const float*)d_in[10];
    const float* b1_u2t  = (const float*)d_in[11];
    const float* W2_u2t  = (const float*)d_in[12];
    const float* as2_u2t = (const float*)d_in[13];
    const float* ad2_u2t = (const float*)d_in[14];
    const float* b2_u2t  = (const float*)d_in[15];
    const float* W1_t2u  = (const float*)d_in[16];
    const float* as1_t2u = (const float*)d_in[17];
    const float* ad1_t2u = (const float*)d_in[18];
    const float* b1_t2u  = (const float*)d_in[19];
    const float* Wc      = (const float*)d_in[24];
    const float* bc      = (const float*)d_in[25];
    float* out = (float*)d_out;
    float* ws  = (float*)d_ws;

    const int* src_u2t = ei_u2t;            // user ids
    const int* dst_u2t = ei_u2t + NE;       // tx ids
    const int* src_t2u = ei_t2u;            // tx ids
    const int* dst_u   = ei_t2u + NE;       // user ids

    // ---- workspace layout (floats) ----
    float* h_tx   = ws;                     //  6,400,000
    float* h_us   = ws + 6400000;           //  3,200,000
    float* hs2    = ws + 9600000;           //  1,600,000  (ald2p/als2p alias here pre-gemm)
    float* als2   = ws + 11200000;          //     50,000
    float* ald2   = ws + 11250000;          //    100,000
    float* als_us = ws + 11350000;          //    200,000  (user src-attn for u2t)
    float* ald_us = ws + 11550000;          //    200,000  (user dst-attn for t2u)
    float* als_tx = ws + 11750000;          //    400,000  (tx src-attn for t2u)
    float* ald_tx = ws + 12150000;          //    400,000  (tx dst-attn for u2t)
    float* agg    = ws + 12550000;          // 25,600,000  (u2t then t2u; u1 in place)
    float* avec   = ws + 38150000;          //      1,536
    float* ald2p = hs2;                     //    400,000  (4 x N_TX, aliases hs2)
    float* als2p = hs2 + 400000;            //    200,000  (4 x N_USER)
    float* ew_t   = ws + 38152000;          //  2,000,000  (4 x NE, csr-order weights u2t)
    float* ew_u   = ws + 40152000;          //  2,000,000  (4 x NE, csr-order weights t2u)
    // ---- int region ----
    int* ibase    = (int*)(ws + 42152000);
    int* deg_t    = ibase;                  //   100,000
    int* deg_u    = ibase + 100000;         //    50,000
    int* rowptr_t = ibase + 150000;         //   100,001
    int* cur_t    = ibase + 250001;         //   100,000
    int* csr_t    = ibase + 350001;         //   500,000
    int* rowptr_u = ibase + 850001;         //    50,001
    int* cur_u    = ibase + 900002;         //    50,000
    int* csr_u    = ibase + 950002;         //   500,000
    int* bsum_t   = ibase + 1450002;        //       512
    int* bsum_u   = ibase + 1450514;        //       512

    float* Msrc_u2t = avec + 0;
    float* Mdst_u2t = avec + 256;
    float* Msrc_t2u = avec + 512;
    float* Mdst_t2u = avec + 768;
    float* vsrc2    = avec + 1024;          // fold(W2, as2): als2 = u1 . vsrc2
    float* vdst2    = avec + 1280;          // fold(W2, ad2): ald2 = t1 . vdst2

    // ---- fold attention vectors into weights ----
    AVArgs6 av;
    av.t[0] = { W1_u2t, as1_u2t, Msrc_u2t, HID, NH, HID };
    av.t[1] = { W1_u2t, ad1_u2t, Mdst_u2t, HID, NH, HID };
    av.t[2] = { W1_t2u, as1_t2u, Msrc_t2u, HID, NH, HID };
    av.t[3] = { W1_t2u, ad1_t2u, Mdst_t2u, HID, NH, HID };
    av.t[4] = { W2_u2t, as2_u2t, vsrc2, HC1, 1, OUTC };
    av.t[5] = { W2_u2t, ad2_u2t, vdst2, HC1, 1, OUTC };
    attn_vecs_kernel<<<6, 256, 0, stream>>>(av);

    // ---- zero degree histograms ----
    hipMemsetAsync(deg_t, 0, 150000 * sizeof(int), stream);

    // ---- CSR histogram + prefix scans (no scatter yet) ----
    hist2_kernel<<<(2 * NE + 255) / 256, 256, 0, stream>>>(dst_u2t, dst_u, deg_t, deg_u);
    block_sum2_kernel<<<NB_T + NB_U, 256, 0, stream>>>(deg_t, bsum_t, deg_u, bsum_u);
    scan_bsum2_kernel<<<1, 512, 0, stream>>>(bsum_t, bsum_u);
    scan_final2_kernel<<<NB_T + NB_U, 256, 0, stream>>>(
        deg_t, bsum_t, rowptr_t, cur_t, deg_u, bsum_u, rowptr_u, cur_u);

    // ---- input projections (both node types, ONE launch) with fused attn epilogue ----
    const int NB1 = (N_TX + 63) / 64;
    const int NB2 = (N_USER + 63) / 64;
    gemm_proj_attn_dual<<<dim3(1, NB1 + NB2), 256, 0, stream>>>(
        x_tx, Wp_tx, bp_tx, h_tx, N_TX, F_TX,
        Mdst_u2t, ald_tx, Msrc_t2u, als_tx, NB1,
        x_user, Wp_user, bp_user, h_us, N_USER, F_USER,
        Msrc_u2t, als_us, Mdst_t2u, ald_us);

    // ---- scatter + edge-weight precompute (both edge types) ----
    scatter2_ew_kernel<<<(2 * NE + 255) / 256, 256, 0, stream>>>(
        src_u2t, dst_u2t, cur_t, csr_t, ew_t, als_us, ald_tx,
        src_t2u, dst_u,   cur_u, csr_u, ew_u, als_tx, ald_us);

    // ================= conv1, u2t (dst = tx): agg -> transform -> ald2 partials ==========
    agg_conv1_kernel<<<(N_TX + 3) / 4, 256, 0, stream>>>(
        rowptr_t, csr_t, h_us, ew_t, agg, N_TX);
    transform_v6<<<dim3((N_TX + 63) / 64, NH), 256, 0, stream>>>(
        agg, W1_u2t, b1_u2t, vdst2, ald2p, nullptr, N_TX, 0);

    // ================= conv1, t2u (dst = user): agg -> transform (u1 in place) ==========
    agg_conv1_kernel<<<(N_USER + 3) / 4, 256, 0, stream>>>(
        rowptr_u, csr_u, h_tx, ew_u, agg, N_USER);
    transform_v6<<<dim3((N_USER + 63) / 64, NH), 256, 0, stream>>>(
        agg, W1_t2u, b1_t2u, vsrc2, als2p, agg, N_USER, 1);
    float* u1 = agg;

    // ---- combine head partials ----
    combine_parts<<<(N_TX + N_USER + 255) / 256, 256, 0, stream>>>(
        ald2p, ald2, N_TX, als2p, als2, N_USER);

    // ================= conv2 projection + fused conv2/classifier =================
    gemm_kernel<<<dim3(1, (N_USER + 63) / 64), 256, 0, stream>>>(
        u1, W2_u2t, nullptr, hs2, N_USER, HC1, OUTC, 0);
    conv2_fused_kernel<<<(N_TX + 3) / 4, 256, 0, stream>>>(
        rowptr_t, csr_t, hs2, als2, ald2, b2_u2t, Wc, bc, out, N_TX);
}

// Round 13
// 564.185 us; speedup vs baseline: 1.0398x; 1.0385x over previous
//
#include <hip/hip_runtime.h>
#include <hip/hip_bf16.h>
#include <math.h>

#define N_TX   100000
#define N_USER 50000
#define F_TX   128
#define F_USER 64
#define HID    64
#define NH     4
#define OUTC   32
#define NE     500000
#define HC1    256          // NH*HID
#define SLOPE  0.2f
#define NB_T   391          // (N_TX+255)/256
#define NB_U   196          // (N_USER+255)/256

__device__ __forceinline__ float elu_f(float x) { return x > 0.f ? x : (expf(x) - 1.f); }
// fast attention-weight exp: softmax normalizes away the ~1ulp v_exp error
__device__ __forceinline__ float lrelu_exp_fast(float x) { x = x > 0.f ? x : SLOPE * x; return __expf(x); }

// row-of-acc FMA: acc[i][0..3] += XS * WV.{x,y,z,w}  (named vars only -> register-resident)
#define ACC_STEP(i, XS, WV) \
    acc[i][0] = fmaf((XS), (WV).x, acc[i][0]); \
    acc[i][1] = fmaf((XS), (WV).y, acc[i][1]); \
    acc[i][2] = fmaf((XS), (WV).z, acc[i][2]); \
    acc[i][3] = fmaf((XS), (WV).w, acc[i][3]);
#define ACC4(i, XV) \
    ACC_STEP(i, (XV).x, w0) ACC_STEP(i, (XV).y, w1) \
    ACC_STEP(i, (XV).z, w2) ACC_STEP(i, (XV).w, w3)

// ---------------- tiled fp32 GEMM: C = act(A[N,K] @ B[K,M] + bias) ----------------
// Pad = 68 floats (272B, 16B-aligned) -> ds_read_b128 operands, conflict-free (r10: -40us).
__global__ __launch_bounds__(256) void gemm_kernel(const float* __restrict__ A,
    const float* __restrict__ B, const float* __restrict__ bias,
    float* __restrict__ C, int N, int K, int M, int act)
{
    __shared__ float As[16][68];
    __shared__ float Bs[16][68];
    const int tid = threadIdx.x;
    const int tx = tid % 16, ty = tid / 16;
    const int row0 = blockIdx.y * 64, col0 = blockIdx.x * 64;
    float acc[4][4] = {};
    for (int k0 = 0; k0 < K; k0 += 16) {
        #pragma unroll
        for (int i = 0; i < 4; ++i) {
            int idx = tid * 4 + i;           // 64x16 A tile
            int r = idx >> 4, kk = idx & 15;
            int gr = row0 + r;
            As[kk][r] = (gr < N) ? A[(size_t)gr * K + (k0 + kk)] : 0.f;
        }
        #pragma unroll
        for (int i = 0; i < 4; ++i) {
            int idx = tid * 4 + i;           // 16x64 B tile
            int kk = idx >> 6, c = idx & 63;
            int gc = col0 + c;
            Bs[kk][c] = (gc < M) ? B[(size_t)(k0 + kk) * M + gc] : 0.f;
        }
        __syncthreads();
        #pragma unroll 2
        for (int kk = 0; kk < 16; ++kk) {
            const float4 av = *(const float4*)(&As[kk][ty * 4]);
            const float4 bv = *(const float4*)(&Bs[kk][tx * 4]);
            ACC_STEP(0, av.x, bv)
            ACC_STEP(1, av.y, bv)
            ACC_STEP(2, av.z, bv)
            ACC_STEP(3, av.w, bv)
        }
        __syncthreads();
    }
    #pragma unroll
    for (int i = 0; i < 4; ++i) {
        int r = row0 + ty * 4 + i;
        if (r >= N) continue;
        #pragma unroll
        for (int j = 0; j < 4; ++j) {
            int c = col0 + tx * 4 + j;
            if (c >= M) continue;
            float v = acc[i][j] + (bias ? bias[c] : 0.f);
            if (act == 1) v = elu_f(v);
            C[(size_t)r * M + c] = v;
        }
    }
}

// ====== DUAL projection GEMM (tx + user in one launch) with fused ELU + attn epilogue ======
// blockIdx.y < NB1 -> tx params; else user params. M==64, grid.x==1 for both.
__global__ __launch_bounds__(256) void gemm_proj_attn_dual(
    const float* __restrict__ A1, const float* __restrict__ B1, const float* __restrict__ bias1,
    float* __restrict__ C1, int N1, int K1,
    const float* __restrict__ Ma1, float* __restrict__ oa1,
    const float* __restrict__ Mb1, float* __restrict__ ob1, int NB1,
    const float* __restrict__ A2, const float* __restrict__ B2, const float* __restrict__ bias2,
    float* __restrict__ C2, int N2, int K2,
    const float* __restrict__ Ma2, float* __restrict__ oa2,
    const float* __restrict__ Mb2, float* __restrict__ ob2)
{
    __shared__ float As[16][68];
    __shared__ float Bs[16][68];
    const int tid = threadIdx.x;
    const int tx = tid % 16, ty = tid / 16;
    const float* A; const float* B; const float* bias; float* C; int N, K;
    const float* Ma; float* oa; const float* Mb; float* ob; int row0;
    if ((int)blockIdx.y < NB1) {
        A = A1; B = B1; bias = bias1; C = C1; N = N1; K = K1;
        Ma = Ma1; oa = oa1; Mb = Mb1; ob = ob1;
        row0 = blockIdx.y * 64;
    } else {
        A = A2; B = B2; bias = bias2; C = C2; N = N2; K = K2;
        Ma = Ma2; oa = oa2; Mb = Mb2; ob = ob2;
        row0 = (blockIdx.y - NB1) * 64;
    }
    float acc[4][4] = {};
    for (int k0 = 0; k0 < K; k0 += 16) {
        #pragma unroll
        for (int i = 0; i < 4; ++i) {
            int idx = tid * 4 + i;           // 64x16 A tile
            int r = idx >> 4, kk = idx & 15;
            int gr = row0 + r;
            As[kk][r] = (gr < N) ? A[(size_t)gr * K + (k0 + kk)] : 0.f;
        }
        #pragma unroll
        for (int i = 0; i < 4; ++i) {
            int idx = tid * 4 + i;           // 16x64 B tile (M==64, no col guard)
            int kk = idx >> 6, c = idx & 63;
            Bs[kk][c] = B[(size_t)(k0 + kk) * 64 + c];
        }
        __syncthreads();
        #pragma unroll 2
        for (int kk = 0; kk < 16; ++kk) {
            const float4 av = *(const float4*)(&As[kk][ty * 4]);
            const float4 bv = *(const float4*)(&Bs[kk][tx * 4]);
            ACC_STEP(0, av.x, bv)
            ACC_STEP(1, av.y, bv)
            ACC_STEP(2, av.z, bv)
            ACC_STEP(3, av.w, bv)
        }
        __syncthreads();
    }
    // ---- epilogue: ELU + store row + fused dots against Ma/Mb ([c][4] layout) ----
    const float4 ma0 = *(const float4*)(Ma + (tx * 4 + 0) * 4);
    const float4 ma1 = *(const float4*)(Ma + (tx * 4 + 1) * 4);
    const float4 ma2 = *(const float4*)(Ma + (tx * 4 + 2) * 4);
    const float4 ma3 = *(const float4*)(Ma + (tx * 4 + 3) * 4);
    const float4 mb0 = *(const float4*)(Mb + (tx * 4 + 0) * 4);
    const float4 mb1 = *(const float4*)(Mb + (tx * 4 + 1) * 4);
    const float4 mb2 = *(const float4*)(Mb + (tx * 4 + 2) * 4);
    const float4 mb3 = *(const float4*)(Mb + (tx * 4 + 3) * 4);
    const float4 bb  = *(const float4*)(bias + tx * 4);
    #pragma unroll
    for (int i = 0; i < 4; ++i) {
        int r = row0 + ty * 4 + i;
        bool wr = (r < N);
        float v0 = acc[i][0] + bb.x; v0 = v0 > 0.f ? v0 : (expf(v0) - 1.f);
        float v1 = acc[i][1] + bb.y; v1 = v1 > 0.f ? v1 : (expf(v1) - 1.f);
        float v2 = acc[i][2] + bb.z; v2 = v2 > 0.f ? v2 : (expf(v2) - 1.f);
        float v3 = acc[i][3] + bb.w; v3 = v3 > 0.f ? v3 : (expf(v3) - 1.f);
        if (wr) *(float4*)(C + (size_t)r * 64 + tx * 4) = make_float4(v0, v1, v2, v3);
        float pax = v0 * ma0.x + v1 * ma1.x + v2 * ma2.x + v3 * ma3.x;
        float pay = v0 * ma0.y + v1 * ma1.y + v2 * ma2.y + v3 * ma3.y;
        float paz = v0 * ma0.z + v1 * ma1.z + v2 * ma2.z + v3 * ma3.z;
        float paw = v0 * ma0.w + v1 * ma1.w + v2 * ma2.w + v3 * ma3.w;
        float pbx = v0 * mb0.x + v1 * mb1.x + v2 * mb2.x + v3 * mb3.x;
        float pby = v0 * mb0.y + v1 * mb1.y + v2 * mb2.y + v3 * mb3.y;
        float pbz = v0 * mb0.z + v1 * mb1.z + v2 * mb2.z + v3 * mb3.z;
        float pbw = v0 * mb0.w + v1 * mb1.w + v2 * mb2.w + v3 * mb3.w;
        #pragma unroll
        for (int off = 1; off < 16; off <<= 1) {
            pax += __shfl_xor(pax, off); pay += __shfl_xor(pay, off);
            paz += __shfl_xor(paz, off); paw += __shfl_xor(paw, off);
            pbx += __shfl_xor(pbx, off); pby += __shfl_xor(pby, off);
            pbz += __shfl_xor(pbz, off); pbw += __shfl_xor(pbw, off);
        }
        if (tx == 0 && wr) {
            *(float4*)(oa + (size_t)r * 4) = make_float4(pax, pay, paz, paw);
            *(float4*)(ob + (size_t)r * 4) = make_float4(pbx, pby, pbz, pbw);
        }
    }
}

// ------------- fold attention vectors into weights: Mv[k,h] = sum_c W[k,h*C+c]*a[h,c] -------------
struct AVArgs  { const float* W; const float* a; float* out; int K; int H; int C; };
struct AVArgs6 { AVArgs t[6]; };

__global__ void attn_vecs_kernel(AVArgs6 args)
{
    AVArgs A = args.t[blockIdx.x];
    int tid = threadIdx.x;
    if (tid < A.K * A.H) {
        int k = tid % A.K, h = tid / A.K;
        float s = 0.f;
        const float* wrow = A.W + (size_t)k * (A.H * A.C) + h * A.C;
        const float* arow = A.a + h * A.C;
        for (int c = 0; c < A.C; ++c) s += wrow[c] * arow[c];
        A.out[k * A.H + h] = s;
    }
}

// ================= merged CSR build (both edge types per launch) =================
__global__ __launch_bounds__(256) void hist2_kernel(const int* __restrict__ dst_t,
    const int* __restrict__ dst_u, int* __restrict__ deg_t, int* __restrict__ deg_u)
{
    int e = blockIdx.x * 256 + threadIdx.x;
    if (e < NE) atomicAdd(&deg_t[dst_t[e]], 1);
    else {
        e -= NE;
        if (e < NE) atomicAdd(&deg_u[dst_u[e]], 1);
    }
}

__global__ __launch_bounds__(256) void block_sum2_kernel(const int* __restrict__ deg_t,
    int* __restrict__ bsum_t, const int* __restrict__ deg_u, int* __restrict__ bsum_u)
{
    __shared__ int lds[256];
    int b = blockIdx.x, t = threadIdx.x;
    const int* deg; int* bsum; int Nd, lb;
    if (b < NB_T) { deg = deg_t; bsum = bsum_t; Nd = N_TX; lb = b; }
    else         { deg = deg_u; bsum = bsum_u; Nd = N_USER; lb = b - NB_T; }
    int i = lb * 256 + t;
    lds[t] = (i < Nd) ? deg[i] : 0;
    __syncthreads();
    for (int o = 128; o > 0; o >>= 1) {
        if (t < o) lds[t] += lds[t + o];
        __syncthreads();
    }
    if (t == 0) bsum[lb] = lds[0];
}

__global__ __launch_bounds__(512) void scan_bsum2_kernel(int* __restrict__ bt,
    int* __restrict__ bu)
{
    __shared__ int lds[512];
    int t = threadIdx.x;
    {
        int v = (t < NB_T) ? bt[t] : 0;
        lds[t] = v;
        __syncthreads();
        for (int o = 1; o < 512; o <<= 1) {
            int x = (t >= o) ? lds[t - o] : 0;
            __syncthreads();
            lds[t] += x;
            __syncthreads();
        }
        if (t < NB_T) bt[t] = lds[t] - v;
        __syncthreads();
    }
    {
        int v = (t < NB_U) ? bu[t] : 0;
        lds[t] = v;
        __syncthreads();
        for (int o = 1; o < 512; o <<= 1) {
            int x = (t >= o) ? lds[t - o] : 0;
            __syncthreads();
            lds[t] += x;
            __syncthreads();
        }
        if (t < NB_U) bu[t] = lds[t] - v;
    }
}

__global__ __launch_bounds__(256) void scan_final2_kernel(
    const int* __restrict__ deg_t, const int* __restrict__ be_t,
    int* __restrict__ rowptr_t, int* __restrict__ cur_t,
    const int* __restrict__ deg_u, const int* __restrict__ be_u,
    int* __restrict__ rowptr_u, int* __restrict__ cur_u)
{
    __shared__ int lds[256];
    int b = blockIdx.x, t = threadIdx.x;
    const int* deg; const int* be; int* rowptr; int* cursor; int Nd, lb;
    if (b < NB_T) { deg = deg_t; be = be_t; rowptr = rowptr_t; cursor = cur_t; Nd = N_TX; lb = b; }
    else         { deg = deg_u; be = be_u; rowptr = rowptr_u; cursor = cur_u; Nd = N_USER; lb = b - NB_T; }
    int i = lb * 256 + t;
    int v = (i < Nd) ? deg[i] : 0;
    lds[t] = v;
    __syncthreads();
    for (int o = 1; o < 256; o <<= 1) {
        int x = (t >= o) ? lds[t - o] : 0;
        __syncthreads();
        lds[t] += x;
        __syncthreads();
    }
    int excl = lds[t] - v + be[lb];
    if (i < Nd) {
        rowptr[i] = excl;
        cursor[i] = excl;
        if (i == Nd - 1) rowptr[Nd] = NE;
    }
}

// ---- scatter + edge-weight precompute into PACKED 32B records {w:float4, s:int, pad} ----
// One edge type per launch. Both 16B stores hit the SAME 64B line (32B-aligned record
// never straddles a line) -> 1 random line/edge instead of 2 (csr[] + ew[] were separate
// arrays = 128B of line traffic/edge; measured WRITE 100MB vs 20MB payload).
__global__ __launch_bounds__(256) void scatter_ew_kernel(
    const int* __restrict__ src, const int* __restrict__ dst,
    int* __restrict__ cur, float* __restrict__ rec,
    const float* __restrict__ als, const float* __restrict__ ald)
{
    int e = blockIdx.x * 256 + threadIdx.x;
    if (e >= NE) return;
    int s = src[e], d = dst[e];
    int p = atomicAdd(&cur[d], 1);
    float4 a = *(const float4*)(als + (size_t)s * 4);
    float4 b = *(const float4*)(ald + (size_t)d * 4);
    float4 w;
    w.x = lrelu_exp_fast(a.x + b.x);
    w.y = lrelu_exp_fast(a.y + b.y);
    w.z = lrelu_exp_fast(a.z + b.z);
    w.w = lrelu_exp_fast(a.w + b.w);
    float* r8 = rec + (size_t)p * 8;
    *(float4*)(r8)     = w;
    *(float4*)(r8 + 4) = make_float4(__int_as_float(s), 0.f, 0.f, 0.f);
}

// ================= conv1 aggregation: one wave per dst node, packed records ==========
__device__ __forceinline__ void acc_edge(int i, int lane,
    const float* __restrict__ rec, const float* __restrict__ hsrc,
    float& a0, float& a1, float& a2, float& a3,
    float& w0, float& w1, float& w2, float& w3)
{
    const float* r8 = rec + (size_t)i * 8;
    float4 e = *(const float4*)(r8);                   // streaming broadcast (same line as s)
    int s = __float_as_int(r8[4]);
    float x = hsrc[(size_t)s * 64 + lane];             // 256B gather
    a0 = fmaf(e.x, x, a0); w0 += e.x;
    a1 = fmaf(e.y, x, a1); w1 += e.y;
    a2 = fmaf(e.z, x, a2); w2 += e.z;
    a3 = fmaf(e.w, x, a3); w3 += e.w;
}

__global__ __launch_bounds__(256) void agg_conv1_kernel(const int* __restrict__ rowptr,
    const float* __restrict__ rec, const float* __restrict__ hsrc,
    float* __restrict__ agg, int Nd)
{
    int d = blockIdx.x * 4 + (threadIdx.x >> 6);
    int lane = threadIdx.x & 63;
    if (d >= Nd) return;
    int beg = rowptr[d], end = rowptr[d + 1];
    float a0 = 0.f, a1 = 0.f, a2 = 0.f, a3 = 0.f;
    float w0 = 0.f, w1 = 0.f, w2 = 0.f, w3 = 0.f;
    int i = beg;
    for (; i + 2 <= end; i += 2) {
        acc_edge(i,     lane, rec, hsrc, a0, a1, a2, a3, w0, w1, w2, w3);
        acc_edge(i + 1, lane, rec, hsrc, a0, a1, a2, a3, w0, w1, w2, w3);
    }
    if (i < end)
        acc_edge(i, lane, rec, hsrc, a0, a1, a2, a3, w0, w1, w2, w3);
    float* o = agg + (size_t)d * 256;
    o[lane]       = a0 / (w0 + 1e-16f);
    o[64 + lane]  = a1 / (w1 + 1e-16f);
    o[128 + lane] = a2 / (w2 + 1e-16f);
    o[192 + lane] = a3 / (w3 + 1e-16f);
}

// ================= conv1 dst-side transform v6 (proven 67-69us): 64-node tile, 4x4/thread ==
// LDS-BW bound at ~1.5x the 46us LDS floor; v8 (bigger tile) lost to occupancy, v9
// (global-direct x) lost to L2 latency -> v6 is the optimum of this fp32 structure.
// `#pragma unroll 1` on the k-loop is load-bearing (r1/r2: full unroll -> cross-iteration
// ds_read hoisting past the VGPR budget -> deterministic 2.5 GB/launch scratch spill).
__global__ __launch_bounds__(256) void transform_v6(
    const float* __restrict__ agg, const float* __restrict__ W1,
    const float* __restrict__ b1, const float* __restrict__ vvec,
    float* __restrict__ dot_part, float* __restrict__ rows_out,
    int Nd, int writeRows)
{
    constexpr int SXP = 68;                   // row stride (floats): 272B, 16B-aligned
    __shared__ float sX[64 * SXP];            // [node][c]
    __shared__ float sW[64 * 64];             // [c][col]
    const int tid  = threadIdx.x;
    const int w    = tid >> 6;
    const int lane = tid & 63;
    const int h    = blockIdx.y;
    const int base = blockIdx.x * 64;

    // ---- stage x tile: wave w stages node rows, 256B contiguous per row ----
    #pragma unroll
    for (int it = 0; it < 4; ++it) {
        int r  = w * 16 + it * 4 + (lane >> 4);
        int c0 = (lane & 15) * 4;
        int g  = base + r;
        float4 v = make_float4(0.f, 0.f, 0.f, 0.f);
        if (g < Nd) v = *(const float4*)(agg + (size_t)g * 256 + h * 64 + c0);
        *(float4*)(sX + r * SXP + c0) = v;
    }
    // ---- stage W head-slice: row c, cols h*64..h*64+63 ----
    #pragma unroll
    for (int it = 0; it < 4; ++it) {
        int c    = w * 16 + it * 4 + (lane >> 4);
        int col0 = (lane & 15) * 4;
        *(float4*)(sW + c * 64 + col0) =
            *(const float4*)(W1 + (size_t)c * 256 + h * 64 + col0);
    }
    __syncthreads();

    const int tx = tid & 15;                  // col group (4 cols)
    const int ty = tid >> 4;                  // node group (4 nodes)
    float acc[4][4] = {};

    #pragma unroll 1
    for (int c0 = 0; c0 < 64; c0 += 4) {
        const float4 x0 = *(const float4*)(sX + (ty * 4 + 0) * SXP + c0);
        const float4 x1 = *(const float4*)(sX + (ty * 4 + 1) * SXP + c0);
        const float4 x2 = *(const float4*)(sX + (ty * 4 + 2) * SXP + c0);
        const float4 x3 = *(const float4*)(sX + (ty * 4 + 3) * SXP + c0);
        const float4 w0 = *(const float4*)(sW + (c0 + 0) * 64 + tx * 4);
        const float4 w1 = *(const float4*)(sW + (c0 + 1) * 64 + tx * 4);
        const float4 w2 = *(const float4*)(sW + (c0 + 2) * 64 + tx * 4);
        const float4 w3 = *(const float4*)(sW + (c0 + 3) * 64 + tx * 4);
        ACC4(0, x0)
        ACC4(1, x1)
        ACC4(2, x2)
        ACC4(3, x3)
    }

    // ---- epilogue: bias + ELU, optional row write, vvec dot-partials ----
    const float4 bb = *(const float4*)(b1   + h * 64 + tx * 4);
    const float4 vv = *(const float4*)(vvec + h * 64 + tx * 4);
    float* dp = dot_part + (size_t)h * Nd;
    #pragma unroll
    for (int i = 0; i < 4; ++i) {
        int g = base + ty * 4 + i;            // uniform across the 16-lane tx group
        if (g >= Nd) continue;
        float v0 = acc[i][0] + bb.x; v0 = v0 > 0.f ? v0 : (expf(v0) - 1.f);
        float v1 = acc[i][1] + bb.y; v1 = v1 > 0.f ? v1 : (expf(v1) - 1.f);
        float v2 = acc[i][2] + bb.z; v2 = v2 > 0.f ? v2 : (expf(v2) - 1.f);
        float v3 = acc[i][3] + bb.w; v3 = v3 > 0.f ? v3 : (expf(v3) - 1.f);
        if (writeRows)
            *(float4*)(rows_out + (size_t)g * 256 + h * 64 + tx * 4) =
                make_float4(v0, v1, v2, v3);
        float s = v0 * vv.x + v1 * vv.y + v2 * vv.z + v3 * vv.w;
        s += __shfl_xor(s, 1); s += __shfl_xor(s, 2);
        s += __shfl_xor(s, 4); s += __shfl_xor(s, 8);
        if (tx == 0) dp[g] = s;
    }
}

// ------------- sum 4 head partials: o1[i] = sum_h ap[h*N1+i]; o2 likewise -------------
__global__ __launch_bounds__(256) void combine_parts(
    const float* __restrict__ ap, float* __restrict__ o1, int N1,
    const float* __restrict__ bp, float* __restrict__ o2, int N2)
{
    int i = blockIdx.x * 256 + threadIdx.x;
    if (i < N1) {
        o1[i] = ap[i] + ap[N1 + i] + ap[2 * N1 + i] + ap[3 * N1 + i];
    } else {
        int j = i - N1;
        if (j < N2)
            o2[j] = bp[j] + bp[N2 + j] + bp[2 * N2 + j] + bp[3 * N2 + j];
    }
}

// ================= conv2: fused edge-softmax + aggregation + bias/ELU + classifier ==========
// src ids come from the packed rec_t records (csr array eliminated).
__global__ __launch_bounds__(256) void conv2_fused_kernel(const int* __restrict__ rowptr,
    const float* __restrict__ rec, const float* __restrict__ hs2,
    const float* __restrict__ als2, const float* __restrict__ ald2,
    const float* __restrict__ b2, const float* __restrict__ Wc, const float* __restrict__ bc,
    float* __restrict__ out, int Nd)
{
    int d = blockIdx.x * 4 + (threadIdx.x >> 6);
    int lane = threadIdx.x & 63;
    if (d >= Nd) return;
    int beg = rowptr[d], end = rowptr[d + 1];
    float aldd = ald2[d];
    int half = lane >> 5, c = lane & 31;
    float acc = 0.f, wsum = 0.f;
    for (int i = beg + half; i < end; i += 2) {
        int s = __float_as_int(rec[(size_t)i * 8 + 4]);
        float w = lrelu_exp_fast(als2[s] + aldd);
        acc = fmaf(w, hs2[(size_t)s * 32 + c], acc);
        wsum += w;
    }
    acc  += __shfl_down(acc, 32);
    wsum += __shfl_down(wsum, 32);
    float val = 0.f;
    if (lane < 32) {
        float t2 = acc / (wsum + 1e-16f) + b2[c];
        t2 = t2 > 0.f ? t2 : (expf(t2) - 1.f);
        val = t2 * Wc[c];
    }
    #pragma unroll
    for (int o = 16; o > 0; o >>= 1) val += __shfl_down(val, o);
    if (lane == 0) out[d] = val + bc[0];
}

extern "C" void kernel_launch(void* const* d_in, const int* in_sizes, int n_in,
                              void* d_out, int out_size, void* d_ws, size_t ws_size,
                              hipStream_t stream)
{
    const float* x_tx    = (const float*)d_in[0];
    const float* x_user  = (const float*)d_in[1];
    const int*   ei_u2t  = (const int*)d_in[2];
    const int*   ei_t2u  = (const int*)d_in[3];
    const float* Wp_tx   = (const float*)d_in[4];
    const float* bp_tx   = (const float*)d_in[5];
    const float* Wp_user = (const float*)d_in[6];
    const float* bp_user = (const float*)d_in[7];
    const float* W1_u2t  = (const float*)d_in[8];
    const float* as1_u2t = (const float*)d_in[9];
    const float* ad1_u2t = (const float*)d_in[10];
    const float* b1_u2t  = (const float*)d_in[11];
    const float* W2_u2t  = (const float*)d_in[12];
    const float* as2_u2t = (const float*)d_in[13];
    const float* ad2_u2t = (const float*)d_in[14];
    const float* b2_u2t  = (const float*)d_in[15];
    const float* W1_t2u  = (const float*)d_in[16];
    const float* as1_t2u = (const float*)d_in[17];
    const float* ad1_t2u = (const float*)d_in[18];
    const float* b1_t2u  = (const float*)d_in[19];
    const float* Wc      = (const float*)d_in[24];
    const float* bc      = (const float*)d_in[25];
    float* out = (float*)d_out;
    float* ws  = (float*)d_ws;

    const int* src_u2t = ei_u2t;            // user ids
    const int* dst_u2t = ei_u2t + NE;       // tx ids
    const int* src_t2u = ei_t2u;            // tx ids
    const int* dst_u   = ei_t2u + NE;       // user ids

    // ---- workspace layout (floats) ----
    float* h_tx   = ws;                     //  6,400,000
    float* h_us   = ws + 6400000;           //  3,200,000
    float* hs2    = ws + 9600000;           //  1,600,000  (ald2p/als2p alias here pre-gemm)
    float* als2   = ws + 11200000;          //     50,000
    float* ald2   = ws + 11250000;          //    100,000
    float* als_us = ws + 11350000;          //    200,000  (user src-attn for u2t)
    float* ald_us = ws + 11550000;          //    200,000  (user dst-attn for t2u)
    float* als_tx = ws + 11750000;          //    400,000  (tx src-attn for t2u)
    float* ald_tx = ws + 12150000;          //    400,000  (tx dst-attn for u2t)
    float* agg    = ws + 12550000;          // 25,600,000  (u2t then t2u; u1 in place)
    float* avec   = ws + 38150000;          //      1,536
    float* ald2p = hs2;                     //    400,000  (4 x N_TX, aliases hs2)
    float* als2p = hs2 + 400000;            //    200,000  (4 x N_USER)
    float* rec_t  = ws + 38152000;          //  4,000,000  (8 x NE packed {w4,s} records, u2t)
    float* rec_u  = agg + 12800000;         //  4,000,000  (upper agg half; tx data dead after
                                            //              transform_t, u-agg writes < 12.8M)
    // ---- int region ----
    int* ibase    = (int*)(ws + 42152000);
    int* deg_t    = ibase;                  //   100,000
    int* deg_u    = ibase + 100000;         //    50,000
    int* rowptr_t = ibase + 150000;         //   100,001
    int* cur_t    = ibase + 250001;         //   100,000
    int* rowptr_u = ibase + 350001;         //    50,001
    int* cur_u    = ibase + 400002;         //    50,000
    int* bsum_t   = ibase + 450052;         //       512
    int* bsum_u   = ibase + 450564;         //       512

    float* Msrc_u2t = avec + 0;
    float* Mdst_u2t = avec + 256;
    float* Msrc_t2u = avec + 512;
    float* Mdst_t2u = avec + 768;
    float* vsrc2    = avec + 1024;          // fold(W2, as2): als2 = u1 . vsrc2
    float* vdst2    = avec + 1280;          // fold(W2, ad2): ald2 = t1 . vdst2

    // ---- fold attention vectors into weights ----
    AVArgs6 av;
    av.t[0] = { W1_u2t, as1_u2t, Msrc_u2t, HID, NH, HID };
    av.t[1] = { W1_u2t, ad1_u2t, Mdst_u2t, HID, NH, HID };
    av.t[2] = { W1_t2u, as1_t2u, Msrc_t2u, HID, NH, HID };
    av.t[3] = { W1_t2u, ad1_t2u, Mdst_t2u, HID, NH, HID };
    av.t[4] = { W2_u2t, as2_u2t, vsrc2, HC1, 1, OUTC };
    av.t[5] = { W2_u2t, ad2_u2t, vdst2, HC1, 1, OUTC };
    attn_vecs_kernel<<<6, 256, 0, stream>>>(av);

    // ---- zero degree histograms ----
    hipMemsetAsync(deg_t, 0, 150000 * sizeof(int), stream);

    // ---- CSR histogram + prefix scans (no scatter yet) ----
    hist2_kernel<<<(2 * NE + 255) / 256, 256, 0, stream>>>(dst_u2t, dst_u, deg_t, deg_u);
    block_sum2_kernel<<<NB_T + NB_U, 256, 0, stream>>>(deg_t, bsum_t, deg_u, bsum_u);
    scan_bsum2_kernel<<<1, 512, 0, stream>>>(bsum_t, bsum_u);
    scan_final2_kernel<<<NB_T + NB_U, 256, 0, stream>>>(
        deg_t, bsum_t, rowptr_t, cur_t, deg_u, bsum_u, rowptr_u, cur_u);

    // ---- input projections (both node types, ONE launch) with fused attn epilogue ----
    const int NB1 = (N_TX + 63) / 64;
    const int NB2 = (N_USER + 63) / 64;
    gemm_proj_attn_dual<<<dim3(1, NB1 + NB2), 256, 0, stream>>>(
        x_tx, Wp_tx, bp_tx, h_tx, N_TX, F_TX,
        Mdst_u2t, ald_tx, Msrc_t2u, als_tx, NB1,
        x_user, Wp_user, bp_user, h_us, N_USER, F_USER,
        Msrc_u2t, als_us, Mdst_t2u, ald_us);

    // ================= conv1, u2t (dst = tx): scatter -> agg -> transform ==========
    scatter_ew_kernel<<<(NE + 255) / 256, 256, 0, stream>>>(
        src_u2t, dst_u2t, cur_t, rec_t, als_us, ald_tx);
    agg_conv1_kernel<<<(N_TX + 3) / 4, 256, 0, stream>>>(
        rowptr_t, rec_t, h_us, agg, N_TX);
    transform_v6<<<dim3((N_TX + 63) / 64, NH), 256, 0, stream>>>(
        agg, W1_u2t, b1_u2t, vdst2, ald2p, nullptr, N_TX, 0);

    // ================= conv1, t2u (dst = user): scatter (rec_u overlays dead upper agg)
    //                   -> agg -> transform (u1 in place, lower 12.8M only) ==========
    scatter_ew_kernel<<<(NE + 255) / 256, 256, 0, stream>>>(
        src_t2u, dst_u, cur_u, rec_u, als_tx, ald_us);
    agg_conv1_kernel<<<(N_USER + 3) / 4, 256, 0, stream>>>(
        rowptr_u, rec_u, h_tx, agg, N_USER);
    transform_v6<<<dim3((N_USER + 63) / 64, NH), 256, 0, stream>>>(
        agg, W1_t2u, b1_t2u, vsrc2, als2p, agg, N_USER, 1);
    float* u1 = agg;

    // ---- combine head partials ----
    combine_parts<<<(N_TX + N_USER + 255) / 256, 256, 0, stream>>>(
        ald2p, ald2, N_TX, als2p, als2, N_USER);

    // ================= conv2 projection + fused conv2/classifier =================
    gemm_kernel<<<dim3(1, (N_USER + 63) / 64), 256, 0, stream>>>(
        u1, W2_u2t, nullptr, hs2, N_USER, HC1, OUTC, 0);
    conv2_fused_kernel<<<(N_TX + 3) / 4, 256, 0, stream>>>(
        rowptr_t, rec_t, hs2, als2, ald2, b2_u2t, Wc, bc, out, N_TX);
}

// Round 14
// 538.512 us; speedup vs baseline: 1.0894x; 1.0477x over previous
//
#include <hip/hip_runtime.h>
#include <hip/hip_bf16.h>
#include <math.h>

#define N_TX   100000
#define N_USER 50000
#define F_TX   128
#define F_USER 64
#define HID    64
#define NH     4
#define OUTC   32
#define NE     500000
#define HC1    256          // NH*HID
#define SLOPE  0.2f
#define NB_T   391          // (N_TX+255)/256
#define NB_U   196          // (N_USER+255)/256

__device__ __forceinline__ float elu_f(float x) { return x > 0.f ? x : (expf(x) - 1.f); }
// fast attention-weight exp: softmax normalizes away the ~1ulp v_exp error
__device__ __forceinline__ float lrelu_exp_fast(float x) { x = x > 0.f ? x : SLOPE * x; return __expf(x); }

// row-of-acc FMA: acc[i][0..3] += XS * WV.{x,y,z,w}  (named vars only -> register-resident)
#define ACC_STEP(i, XS, WV) \
    acc[i][0] = fmaf((XS), (WV).x, acc[i][0]); \
    acc[i][1] = fmaf((XS), (WV).y, acc[i][1]); \
    acc[i][2] = fmaf((XS), (WV).z, acc[i][2]); \
    acc[i][3] = fmaf((XS), (WV).w, acc[i][3]);
#define ACC4(i, XV) \
    ACC_STEP(i, (XV).x, w0) ACC_STEP(i, (XV).y, w1) \
    ACC_STEP(i, (XV).z, w2) ACC_STEP(i, (XV).w, w3)

// ====== DUAL projection GEMM (tx + user in one launch) with fused ELU + attn epilogue ======
// blockIdx.y < NB1 -> tx params; else user params. M==64, grid.x==1 for both.
// Pad = 68 floats (272B, 16B-aligned) -> ds_read_b128 operands, conflict-free (r10: -40us).
__global__ __launch_bounds__(256) void gemm_proj_attn_dual(
    const float* __restrict__ A1, const float* __restrict__ B1, const float* __restrict__ bias1,
    float* __restrict__ C1, int N1, int K1,
    const float* __restrict__ Ma1, float* __restrict__ oa1,
    const float* __restrict__ Mb1, float* __restrict__ ob1, int NB1,
    const float* __restrict__ A2, const float* __restrict__ B2, const float* __restrict__ bias2,
    float* __restrict__ C2, int N2, int K2,
    const float* __restrict__ Ma2, float* __restrict__ oa2,
    const float* __restrict__ Mb2, float* __restrict__ ob2)
{
    __shared__ float As[16][68];
    __shared__ float Bs[16][68];
    const int tid = threadIdx.x;
    const int tx = tid % 16, ty = tid / 16;
    const float* A; const float* B; const float* bias; float* C; int N, K;
    const float* Ma; float* oa; const float* Mb; float* ob; int row0;
    if ((int)blockIdx.y < NB1) {
        A = A1; B = B1; bias = bias1; C = C1; N = N1; K = K1;
        Ma = Ma1; oa = oa1; Mb = Mb1; ob = ob1;
        row0 = blockIdx.y * 64;
    } else {
        A = A2; B = B2; bias = bias2; C = C2; N = N2; K = K2;
        Ma = Ma2; oa = oa2; Mb = Mb2; ob = ob2;
        row0 = (blockIdx.y - NB1) * 64;
    }
    float acc[4][4] = {};
    for (int k0 = 0; k0 < K; k0 += 16) {
        #pragma unroll
        for (int i = 0; i < 4; ++i) {
            int idx = tid * 4 + i;           // 64x16 A tile
            int r = idx >> 4, kk = idx & 15;
            int gr = row0 + r;
            As[kk][r] = (gr < N) ? A[(size_t)gr * K + (k0 + kk)] : 0.f;
        }
        #pragma unroll
        for (int i = 0; i < 4; ++i) {
            int idx = tid * 4 + i;           // 16x64 B tile (M==64, no col guard)
            int kk = idx >> 6, c = idx & 63;
            Bs[kk][c] = B[(size_t)(k0 + kk) * 64 + c];
        }
        __syncthreads();
        #pragma unroll 2
        for (int kk = 0; kk < 16; ++kk) {
            const float4 av = *(const float4*)(&As[kk][ty * 4]);
            const float4 bv = *(const float4*)(&Bs[kk][tx * 4]);
            ACC_STEP(0, av.x, bv)
            ACC_STEP(1, av.y, bv)
            ACC_STEP(2, av.z, bv)
            ACC_STEP(3, av.w, bv)
        }
        __syncthreads();
    }
    // ---- epilogue: ELU + store row + fused dots against Ma/Mb ([c][4] layout) ----
    const float4 ma0 = *(const float4*)(Ma + (tx * 4 + 0) * 4);
    const float4 ma1 = *(const float4*)(Ma + (tx * 4 + 1) * 4);
    const float4 ma2 = *(const float4*)(Ma + (tx * 4 + 2) * 4);
    const float4 ma3 = *(const float4*)(Ma + (tx * 4 + 3) * 4);
    const float4 mb0 = *(const float4*)(Mb + (tx * 4 + 0) * 4);
    const float4 mb1 = *(const float4*)(Mb + (tx * 4 + 1) * 4);
    const float4 mb2 = *(const float4*)(Mb + (tx * 4 + 2) * 4);
    const float4 mb3 = *(const float4*)(Mb + (tx * 4 + 3) * 4);
    const float4 bb  = *(const float4*)(bias + tx * 4);
    #pragma unroll
    for (int i = 0; i < 4; ++i) {
        int r = row0 + ty * 4 + i;
        bool wr = (r < N);
        float v0 = acc[i][0] + bb.x; v0 = v0 > 0.f ? v0 : (expf(v0) - 1.f);
        float v1 = acc[i][1] + bb.y; v1 = v1 > 0.f ? v1 : (expf(v1) - 1.f);
        float v2 = acc[i][2] + bb.z; v2 = v2 > 0.f ? v2 : (expf(v2) - 1.f);
        float v3 = acc[i][3] + bb.w; v3 = v3 > 0.f ? v3 : (expf(v3) - 1.f);
        if (wr) *(float4*)(C + (size_t)r * 64 + tx * 4) = make_float4(v0, v1, v2, v3);
        float pax = v0 * ma0.x + v1 * ma1.x + v2 * ma2.x + v3 * ma3.x;
        float pay = v0 * ma0.y + v1 * ma1.y + v2 * ma2.y + v3 * ma3.y;
        float paz = v0 * ma0.z + v1 * ma1.z + v2 * ma2.z + v3 * ma3.z;
        float paw = v0 * ma0.w + v1 * ma1.w + v2 * ma2.w + v3 * ma3.w;
        float pbx = v0 * mb0.x + v1 * mb1.x + v2 * mb2.x + v3 * mb3.x;
        float pby = v0 * mb0.y + v1 * mb1.y + v2 * mb2.y + v3 * mb3.y;
        float pbz = v0 * mb0.z + v1 * mb1.z + v2 * mb2.z + v3 * mb3.z;
        float pbw = v0 * mb0.w + v1 * mb1.w + v2 * mb2.w + v3 * mb3.w;
        #pragma unroll
        for (int off = 1; off < 16; off <<= 1) {
            pax += __shfl_xor(pax, off); pay += __shfl_xor(pay, off);
            paz += __shfl_xor(paz, off); paw += __shfl_xor(paw, off);
            pbx += __shfl_xor(pbx, off); pby += __shfl_xor(pby, off);
            pbz += __shfl_xor(pbz, off); pbw += __shfl_xor(pbw, off);
        }
        if (tx == 0 && wr) {
            *(float4*)(oa + (size_t)r * 4) = make_float4(pax, pay, paz, paw);
            *(float4*)(ob + (size_t)r * 4) = make_float4(pbx, pby, pbz, pbw);
        }
    }
}

// ------------- fold attention vectors into weights: Mv[k,h] = sum_c W[k,h*C+c]*a[h,c] -------------
struct AVArgs  { const float* W; const float* a; float* out; int K; int H; int C; };
struct AVArgs6 { AVArgs t[6]; };

__global__ void attn_vecs_kernel(AVArgs6 args)
{
    AVArgs A = args.t[blockIdx.x];
    int tid = threadIdx.x;
    if (tid < A.K * A.H) {
        int k = tid % A.K, h = tid / A.K;
        float s = 0.f;
        const float* wrow = A.W + (size_t)k * (A.H * A.C) + h * A.C;
        const float* arow = A.a + h * A.C;
        for (int c = 0; c < A.C; ++c) s += wrow[c] * arow[c];
        A.out[k * A.H + h] = s;
    }
}

// ================= merged CSR build (both edge types per launch) =================
__global__ __launch_bounds__(256) void hist2_kernel(const int* __restrict__ dst_t,
    const int* __restrict__ dst_u, int* __restrict__ deg_t, int* __restrict__ deg_u)
{
    int e = blockIdx.x * 256 + threadIdx.x;
    if (e < NE) atomicAdd(&deg_t[dst_t[e]], 1);
    else {
        e -= NE;
        if (e < NE) atomicAdd(&deg_u[dst_u[e]], 1);
    }
}

__global__ __launch_bounds__(256) void block_sum2_kernel(const int* __restrict__ deg_t,
    int* __restrict__ bsum_t, const int* __restrict__ deg_u, int* __restrict__ bsum_u)
{
    __shared__ int lds[256];
    int b = blockIdx.x, t = threadIdx.x;
    const int* deg; int* bsum; int Nd, lb;
    if (b < NB_T) { deg = deg_t; bsum = bsum_t; Nd = N_TX; lb = b; }
    else         { deg = deg_u; bsum = bsum_u; Nd = N_USER; lb = b - NB_T; }
    int i = lb * 256 + t;
    lds[t] = (i < Nd) ? deg[i] : 0;
    __syncthreads();
    for (int o = 128; o > 0; o >>= 1) {
        if (t < o) lds[t] += lds[t + o];
        __syncthreads();
    }
    if (t == 0) bsum[lb] = lds[0];
}

__global__ __launch_bounds__(512) void scan_bsum2_kernel(int* __restrict__ bt,
    int* __restrict__ bu)
{
    __shared__ int lds[512];
    int t = threadIdx.x;
    {
        int v = (t < NB_T) ? bt[t] : 0;
        lds[t] = v;
        __syncthreads();
        for (int o = 1; o < 512; o <<= 1) {
            int x = (t >= o) ? lds[t - o] : 0;
            __syncthreads();
            lds[t] += x;
            __syncthreads();
        }
        if (t < NB_T) bt[t] = lds[t] - v;
        __syncthreads();
    }
    {
        int v = (t < NB_U) ? bu[t] : 0;
        lds[t] = v;
        __syncthreads();
        for (int o = 1; o < 512; o <<= 1) {
            int x = (t >= o) ? lds[t - o] : 0;
            __syncthreads();
            lds[t] += x;
            __syncthreads();
        }
        if (t < NB_U) bu[t] = lds[t] - v;
    }
}

__global__ __launch_bounds__(256) void scan_final2_kernel(
    const int* __restrict__ deg_t, const int* __restrict__ be_t,
    int* __restrict__ rowptr_t, int* __restrict__ cur_t,
    const int* __restrict__ deg_u, const int* __restrict__ be_u,
    int* __restrict__ rowptr_u, int* __restrict__ cur_u)
{
    __shared__ int lds[256];
    int b = blockIdx.x, t = threadIdx.x;
    const int* deg; const int* be; int* rowptr; int* cursor; int Nd, lb;
    if (b < NB_T) { deg = deg_t; be = be_t; rowptr = rowptr_t; cursor = cur_t; Nd = N_TX; lb = b; }
    else         { deg = deg_u; be = be_u; rowptr = rowptr_u; cursor = cur_u; Nd = N_USER; lb = b - NB_T; }
    int i = lb * 256 + t;
    int v = (i < Nd) ? deg[i] : 0;
    lds[t] = v;
    __syncthreads();
    for (int o = 1; o < 256; o <<= 1) {
        int x = (t >= o) ? lds[t - o] : 0;
        __syncthreads();
        lds[t] += x;
        __syncthreads();
    }
    int excl = lds[t] - v + be[lb];
    if (i < Nd) {
        rowptr[i] = excl;
        cursor[i] = excl;
        if (i == Nd - 1) rowptr[Nd] = NE;
    }
}

// ---- scatter + edge-weight precompute into PACKED 32B records {w:float4, s:int, pad} ----
// Both 16B stores hit the SAME 64B line -> 1 random line/edge (r13: -22us vs split arrays).
__global__ __launch_bounds__(256) void scatter_ew_kernel(
    const int* __restrict__ src, const int* __restrict__ dst,
    int* __restrict__ cur, float* __restrict__ rec,
    const float* __restrict__ als, const float* __restrict__ ald)
{
    int e = blockIdx.x * 256 + threadIdx.x;
    if (e >= NE) return;
    int s = src[e], d = dst[e];
    int p = atomicAdd(&cur[d], 1);
    float4 a = *(const float4*)(als + (size_t)s * 4);
    float4 b = *(const float4*)(ald + (size_t)d * 4);
    float4 w;
    w.x = lrelu_exp_fast(a.x + b.x);
    w.y = lrelu_exp_fast(a.y + b.y);
    w.z = lrelu_exp_fast(a.z + b.z);
    w.w = lrelu_exp_fast(a.w + b.w);
    float* r8 = rec + (size_t)p * 8;
    *(float4*)(r8)     = w;
    *(float4*)(r8 + 4) = make_float4(__int_as_float(s), 0.f, 0.f, 0.f);
}

// ================= conv1 aggregation: one wave per dst node, packed records ==========
__device__ __forceinline__ void acc_edge(int i, int lane,
    const float* __restrict__ rec, const float* __restrict__ hsrc,
    float& a0, float& a1, float& a2, float& a3,
    float& w0, float& w1, float& w2, float& w3)
{
    const float* r8 = rec + (size_t)i * 8;
    float4 e = *(const float4*)(r8);                   // streaming broadcast (same line as s)
    int s = __float_as_int(r8[4]);
    float x = hsrc[(size_t)s * 64 + lane];             // 256B gather
    a0 = fmaf(e.x, x, a0); w0 += e.x;
    a1 = fmaf(e.y, x, a1); w1 += e.y;
    a2 = fmaf(e.z, x, a2); w2 += e.z;
    a3 = fmaf(e.w, x, a3); w3 += e.w;
}

__global__ __launch_bounds__(256) void agg_conv1_kernel(const int* __restrict__ rowptr,
    const float* __restrict__ rec, const float* __restrict__ hsrc,
    float* __restrict__ agg, int Nd)
{
    int d = blockIdx.x * 4 + (threadIdx.x >> 6);
    int lane = threadIdx.x & 63;
    if (d >= Nd) return;
    int beg = rowptr[d], end = rowptr[d + 1];
    float a0 = 0.f, a1 = 0.f, a2 = 0.f, a3 = 0.f;
    float w0 = 0.f, w1 = 0.f, w2 = 0.f, w3 = 0.f;
    int i = beg;
    for (; i + 2 <= end; i += 2) {
        acc_edge(i,     lane, rec, hsrc, a0, a1, a2, a3, w0, w1, w2, w3);
        acc_edge(i + 1, lane, rec, hsrc, a0, a1, a2, a3, w0, w1, w2, w3);
    }
    if (i < end)
        acc_edge(i, lane, rec, hsrc, a0, a1, a2, a3, w0, w1, w2, w3);
    float* o = agg + (size_t)d * 256;
    o[lane]       = a0 / (w0 + 1e-16f);
    o[64 + lane]  = a1 / (w1 + 1e-16f);
    o[128 + lane] = a2 / (w2 + 1e-16f);
    o[192 + lane] = a3 / (w3 + 1e-16f);
}

// ========== conv1 dst-side transform v10: v6 core + optional fused hs2 partial GEMM ========
// Core (proven 67-69us): 64-node tile per head, 4x4/thread, LDS-BW bound; `#pragma unroll 1`
// load-bearing (r1/r2 scratch-spill). fuse2==1 (user side): instead of materializing u1
// (51MB write + 51MB gemm re-read + launch), the ELU'd y tile is parked in the dead sX
// buffer and multiplied by the head's W2 slice [64x32] -> per-head hs2 partials (25.6MB);
// combine3 sums them. u1 is never written.
__global__ __launch_bounds__(256) void transform_v10(
    const float* __restrict__ agg, const float* __restrict__ W1,
    const float* __restrict__ b1, const float* __restrict__ vvec,
    float* __restrict__ dot_part, const float* __restrict__ W2,
    float* __restrict__ hs2p, int Nd, int fuse2)
{
    constexpr int SXP = 68;                   // row stride (floats): 272B, 16B-aligned
    __shared__ float sX[64 * SXP];            // [node][c]; reused as y-buffer in phase 2
    __shared__ float sW[64 * 64];             // [c][col]; reused for W2 slice in phase 2
    const int tid  = threadIdx.x;
    const int w    = tid >> 6;
    const int lane = tid & 63;
    const int h    = blockIdx.y;
    const int base = blockIdx.x * 64;

    // ---- stage x tile: wave w stages node rows, 256B contiguous per row ----
    #pragma unroll
    for (int it = 0; it < 4; ++it) {
        int r  = w * 16 + it * 4 + (lane >> 4);
        int c0 = (lane & 15) * 4;
        int g  = base + r;
        float4 v = make_float4(0.f, 0.f, 0.f, 0.f);
        if (g < Nd) v = *(const float4*)(agg + (size_t)g * 256 + h * 64 + c0);
        *(float4*)(sX + r * SXP + c0) = v;
    }
    // ---- stage W head-slice: row c, cols h*64..h*64+63 ----
    #pragma unroll
    for (int it = 0; it < 4; ++it) {
        int c    = w * 16 + it * 4 + (lane >> 4);
        int col0 = (lane & 15) * 4;
        *(float4*)(sW + c * 64 + col0) =
            *(const float4*)(W1 + (size_t)c * 256 + h * 64 + col0);
    }
    __syncthreads();

    const int tx = tid & 15;                  // col group (4 cols)
    const int ty = tid >> 4;                  // node group (4 nodes)
    float acc[4][4] = {};

    #pragma unroll 1
    for (int c0 = 0; c0 < 64; c0 += 4) {
        const float4 x0 = *(const float4*)(sX + (ty * 4 + 0) * SXP + c0);
        const float4 x1 = *(const float4*)(sX + (ty * 4 + 1) * SXP + c0);
        const float4 x2 = *(const float4*)(sX + (ty * 4 + 2) * SXP + c0);
        const float4 x3 = *(const float4*)(sX + (ty * 4 + 3) * SXP + c0);
        const float4 w0 = *(const float4*)(sW + (c0 + 0) * 64 + tx * 4);
        const float4 w1 = *(const float4*)(sW + (c0 + 1) * 64 + tx * 4);
        const float4 w2 = *(const float4*)(sW + (c0 + 2) * 64 + tx * 4);
        const float4 w3 = *(const float4*)(sW + (c0 + 3) * 64 + tx * 4);
        ACC4(0, x0)
        ACC4(1, x1)
        ACC4(2, x2)
        ACC4(3, x3)
    }
    __syncthreads();   // all sX/sW reads drained before phase-2 reuse

    // ---- epilogue: bias + ELU, dot-partials; fuse2: park y in sX ----
    const float4 bb = *(const float4*)(b1   + h * 64 + tx * 4);
    const float4 vv = *(const float4*)(vvec + h * 64 + tx * 4);
    float* dp = dot_part + (size_t)h * Nd;
    #pragma unroll
    for (int i = 0; i < 4; ++i) {
        int g = base + ty * 4 + i;            // uniform across the 16-lane tx group
        float v0 = acc[i][0] + bb.x; v0 = v0 > 0.f ? v0 : (expf(v0) - 1.f);
        float v1 = acc[i][1] + bb.y; v1 = v1 > 0.f ? v1 : (expf(v1) - 1.f);
        float v2 = acc[i][2] + bb.z; v2 = v2 > 0.f ? v2 : (expf(v2) - 1.f);
        float v3 = acc[i][3] + bb.w; v3 = v3 > 0.f ? v3 : (expf(v3) - 1.f);
        if (fuse2)                            // OOB rows hold elu(bias) (finite), discarded later
            *(float4*)(sX + (ty * 4 + i) * SXP + tx * 4) = make_float4(v0, v1, v2, v3);
        float s = v0 * vv.x + v1 * vv.y + v2 * vv.z + v3 * vv.w;
        s += __shfl_xor(s, 1); s += __shfl_xor(s, 2);
        s += __shfl_xor(s, 4); s += __shfl_xor(s, 8);
        if (tx == 0 && g < Nd) dp[g] = s;
    }

    if (!fuse2) return;

    // ---- phase 2: hs2 partial = y[64x64] . W2[h*64..h*64+63][0..31] ----
    {
        int idx0 = tid * 8;                   // 2048 floats = 64 rows x 32 cols
        int r = idx0 >> 5, j0 = idx0 & 31;
        const float* wsrc = W2 + (size_t)(h * 64 + r) * 32 + j0;
        *(float4*)(sW + r * 32 + j0)     = *(const float4*)(wsrc);
        *(float4*)(sW + r * 32 + j0 + 4) = *(const float4*)(wsrc + 4);
    }
    __syncthreads();

    float a2[4][2] = {};
    #pragma unroll 1
    for (int r0 = 0; r0 < 64; r0 += 4) {
        const float4 y0 = *(const float4*)(sX + (ty * 4 + 0) * SXP + r0);
        const float4 y1 = *(const float4*)(sX + (ty * 4 + 1) * SXP + r0);
        const float4 y2 = *(const float4*)(sX + (ty * 4 + 2) * SXP + r0);
        const float4 y3 = *(const float4*)(sX + (ty * 4 + 3) * SXP + r0);
        const float2 wA = *(const float2*)(sW + (r0 + 0) * 32 + tx * 2);
        const float2 wB = *(const float2*)(sW + (r0 + 1) * 32 + tx * 2);
        const float2 wC = *(const float2*)(sW + (r0 + 2) * 32 + tx * 2);
        const float2 wD = *(const float2*)(sW + (r0 + 3) * 32 + tx * 2);
        #define P2(i, YV) \
            a2[i][0] = fmaf((YV).x, wA.x, a2[i][0]); a2[i][1] = fmaf((YV).x, wA.y, a2[i][1]); \
            a2[i][0] = fmaf((YV).y, wB.x, a2[i][0]); a2[i][1] = fmaf((YV).y, wB.y, a2[i][1]); \
            a2[i][0] = fmaf((YV).z, wC.x, a2[i][0]); a2[i][1] = fmaf((YV).z, wC.y, a2[i][1]); \
            a2[i][0] = fmaf((YV).w, wD.x, a2[i][0]); a2[i][1] = fmaf((YV).w, wD.y, a2[i][1]);
        P2(0, y0) P2(1, y1) P2(2, y2) P2(3, y3)
        #undef P2
    }
    float* hp = hs2p + (size_t)h * ((size_t)N_USER * 32);
    #pragma unroll
    for (int i = 0; i < 4; ++i) {
        int g = base + ty * 4 + i;
        if (g < Nd)
            *(float2*)(hp + (size_t)g * 32 + tx * 2) = make_float2(a2[i][0], a2[i][1]);
    }
}

// ------ combine3: ald2 = sum_h ald2p; als2 = sum_h als2p; hs2 = sum_h hs2p ------
__global__ __launch_bounds__(256) void combine3_kernel(
    const float* __restrict__ ap, float* __restrict__ o1,
    const float* __restrict__ bp, float* __restrict__ o2,
    const float* __restrict__ hp, float* __restrict__ o3)
{
    int i = blockIdx.x * 256 + threadIdx.x;
    if (i < N_TX) {
        o1[i] = ap[i] + ap[N_TX + i] + ap[2 * N_TX + i] + ap[3 * N_TX + i];
    } else if (i < N_TX + N_USER) {
        int j = i - N_TX;
        o2[j] = bp[j] + bp[N_USER + j] + bp[2 * N_USER + j] + bp[3 * N_USER + j];
    } else {
        int k = i - N_TX - N_USER;
        const int HS = N_USER * 32;
        if (k < HS)
            o3[k] = hp[k] + hp[HS + k] + hp[2 * HS + k] + hp[3 * HS + k];
    }
}

// ================= conv2: fused edge-softmax + aggregation + bias/ELU + classifier ==========
// src ids come from the packed rec_t records (csr array eliminated).
__global__ __launch_bounds__(256) void conv2_fused_kernel(const int* __restrict__ rowptr,
    const float* __restrict__ rec, const float* __restrict__ hs2,
    const float* __restrict__ als2, const float* __restrict__ ald2,
    const float* __restrict__ b2, const float* __restrict__ Wc, const float* __restrict__ bc,
    float* __restrict__ out, int Nd)
{
    int d = blockIdx.x * 4 + (threadIdx.x >> 6);
    int lane = threadIdx.x & 63;
    if (d >= Nd) return;
    int beg = rowptr[d], end = rowptr[d + 1];
    float aldd = ald2[d];
    int half = lane >> 5, c = lane & 31;
    float acc = 0.f, wsum = 0.f;
    for (int i = beg + half; i < end; i += 2) {
        int s = __float_as_int(rec[(size_t)i * 8 + 4]);
        float w = lrelu_exp_fast(als2[s] + aldd);
        acc = fmaf(w, hs2[(size_t)s * 32 + c], acc);
        wsum += w;
    }
    acc  += __shfl_down(acc, 32);
    wsum += __shfl_down(wsum, 32);
    float val = 0.f;
    if (lane < 32) {
        float t2 = acc / (wsum + 1e-16f) + b2[c];
        t2 = t2 > 0.f ? t2 : (expf(t2) - 1.f);
        val = t2 * Wc[c];
    }
    #pragma unroll
    for (int o = 16; o > 0; o >>= 1) val += __shfl_down(val, o);
    if (lane == 0) out[d] = val + bc[0];
}

extern "C" void kernel_launch(void* const* d_in, const int* in_sizes, int n_in,
                              void* d_out, int out_size, void* d_ws, size_t ws_size,
                              hipStream_t stream)
{
    const float* x_tx    = (const float*)d_in[0];
    const float* x_user  = (const float*)d_in[1];
    const int*   ei_u2t  = (const int*)d_in[2];
    const int*   ei_t2u  = (const int*)d_in[3];
    const float* Wp_tx   = (const float*)d_in[4];
    const float* bp_tx   = (const float*)d_in[5];
    const float* Wp_user = (const float*)d_in[6];
    const float* bp_user = (const float*)d_in[7];
    const float* W1_u2t  = (const float*)d_in[8];
    const float* as1_u2t = (const float*)d_in[9];
    const float* ad1_u2t = (const float*)d_in[10];
    const float* b1_u2t  = (const float*)d_in[11];
    const float* W2_u2t  = (const float*)d_in[12];
    const float* as2_u2t = (const float*)d_in[13];
    const float* ad2_u2t = (const float*)d_in[14];
    const float* b2_u2t  = (const float*)d_in[15];
    const float* W1_t2u  = (const float*)d_in[16];
    const float* as1_t2u = (const float*)d_in[17];
    const float* ad1_t2u = (const float*)d_in[18];
    const float* b1_t2u  = (const float*)d_in[19];
    const float* Wc      = (const float*)d_in[24];
    const float* bc      = (const float*)d_in[25];
    float* out = (float*)d_out;
    float* ws  = (float*)d_ws;

    const int* src_u2t = ei_u2t;            // user ids
    const int* dst_u2t = ei_u2t + NE;       // tx ids
    const int* src_t2u = ei_t2u;            // tx ids
    const int* dst_u   = ei_t2u + NE;       // user ids

    // ---- workspace layout (floats) ----
    float* h_tx   = ws;                     //  6,400,000
    float* h_us   = ws + 6400000;           //  3,200,000
    float* parts  = ws + 9600000;           //    600,000  (ald2p 4xN_TX, als2p 4xN_USER)
    float* als2   = ws + 11200000;          //     50,000
    float* ald2   = ws + 11250000;          //    100,000
    float* als_us = ws + 11350000;          //    200,000  (user src-attn for u2t)
    float* ald_us = ws + 11550000;          //    200,000  (user dst-attn for t2u)
    float* als_tx = ws + 11750000;          //    400,000  (tx src-attn for t2u)
    float* ald_tx = ws + 12150000;          //    400,000  (tx dst-attn for u2t)
    float* agg    = ws + 12550000;          // 25,600,000  (tx agg; user agg in lower 12.8M;
                                            //  dead tx zone reused: rec_u, hs2p, hs2f)
    float* avec   = ws + 38150000;          //      1,536
    float* ald2p = parts;                   //    400,000  (4 x N_TX)
    float* als2p = parts + 400000;          //    200,000  (4 x N_USER)
    float* rec_t  = ws + 38152000;          //  4,000,000  (8 x NE packed {w4,s} records, u2t)
    float* rec_u  = agg + 12800000;         //  4,000,000  (dead tx-agg zone after transform_t)
    float* hs2p   = agg + 17000000;         //  6,400,000  (4 x N_USER x 32 partials)
    float* hs2f   = agg + 23500000;         //  1,600,000  (final hs2; ends 25.1M < 25.6M)
    // ---- int region ----
    int* ibase    = (int*)(ws + 42152000);
    int* deg_t    = ibase;                  //   100,000
    int* deg_u    = ibase + 100000;         //    50,000
    int* rowptr_t = ibase + 150000;         //   100,001
    int* cur_t    = ibase + 250001;         //   100,000
    int* rowptr_u = ibase + 350001;         //    50,001
    int* cur_u    = ibase + 400002;         //    50,000
    int* bsum_t   = ibase + 450052;         //       512
    int* bsum_u   = ibase + 450564;         //       512

    float* Msrc_u2t = avec + 0;
    float* Mdst_u2t = avec + 256;
    float* Msrc_t2u = avec + 512;
    float* Mdst_t2u = avec + 768;
    float* vsrc2    = avec + 1024;          // fold(W2, as2): als2 = u1 . vsrc2
    float* vdst2    = avec + 1280;          // fold(W2, ad2): ald2 = t1 . vdst2

    // ---- fold attention vectors into weights ----
    AVArgs6 av;
    av.t[0] = { W1_u2t, as1_u2t, Msrc_u2t, HID, NH, HID };
    av.t[1] = { W1_u2t, ad1_u2t, Mdst_u2t, HID, NH, HID };
    av.t[2] = { W1_t2u, as1_t2u, Msrc_t2u, HID, NH, HID };
    av.t[3] = { W1_t2u, ad1_t2u, Mdst_t2u, HID, NH, HID };
    av.t[4] = { W2_u2t, as2_u2t, vsrc2, HC1, 1, OUTC };
    av.t[5] = { W2_u2t, ad2_u2t, vdst2, HC1, 1, OUTC };
    attn_vecs_kernel<<<6, 256, 0, stream>>>(av);

    // ---- zero degree histograms ----
    hipMemsetAsync(deg_t, 0, 150000 * sizeof(int), stream);

    // ---- CSR histogram + prefix scans (no scatter yet) ----
    hist2_kernel<<<(2 * NE + 255) / 256, 256, 0, stream>>>(dst_u2t, dst_u, deg_t, deg_u);
    block_sum2_kernel<<<NB_T + NB_U, 256, 0, stream>>>(deg_t, bsum_t, deg_u, bsum_u);
    scan_bsum2_kernel<<<1, 512, 0, stream>>>(bsum_t, bsum_u);
    scan_final2_kernel<<<NB_T + NB_U, 256, 0, stream>>>(
        deg_t, bsum_t, rowptr_t, cur_t, deg_u, bsum_u, rowptr_u, cur_u);

    // ---- input projections (both node types, ONE launch) with fused attn epilogue ----
    const int NB1 = (N_TX + 63) / 64;
    const int NB2 = (N_USER + 63) / 64;
    gemm_proj_attn_dual<<<dim3(1, NB1 + NB2), 256, 0, stream>>>(
        x_tx, Wp_tx, bp_tx, h_tx, N_TX, F_TX,
        Mdst_u2t, ald_tx, Msrc_t2u, als_tx, NB1,
        x_user, Wp_user, bp_user, h_us, N_USER, F_USER,
        Msrc_u2t, als_us, Mdst_t2u, ald_us);

    // ================= conv1, u2t (dst = tx): scatter -> agg -> transform ==========
    scatter_ew_kernel<<<(NE + 255) / 256, 256, 0, stream>>>(
        src_u2t, dst_u2t, cur_t, rec_t, als_us, ald_tx);
    agg_conv1_kernel<<<(N_TX + 3) / 4, 256, 0, stream>>>(
        rowptr_t, rec_t, h_us, agg, N_TX);
    transform_v10<<<dim3((N_TX + 63) / 64, NH), 256, 0, stream>>>(
        agg, W1_u2t, b1_u2t, vdst2, ald2p, nullptr, nullptr, N_TX, 0);

    // ================= conv1, t2u (dst = user): scatter (rec_u in dead tx-agg zone)
    //     -> agg (lower 12.8M) -> transform + fused hs2 partials (u1 never written) ==========
    scatter_ew_kernel<<<(NE + 255) / 256, 256, 0, stream>>>(
        src_t2u, dst_u, cur_u, rec_u, als_tx, ald_us);
    agg_conv1_kernel<<<(N_USER + 3) / 4, 256, 0, stream>>>(
        rowptr_u, rec_u, h_tx, agg, N_USER);
    transform_v10<<<dim3((N_USER + 63) / 64, NH), 256, 0, stream>>>(
        agg, W1_t2u, b1_t2u, vsrc2, als2p, W2_u2t, hs2p, N_USER, 1);

    // ---- combine head partials (ald2, als2, hs2) ----
    combine3_kernel<<<(N_TX + N_USER + N_USER * 32 + 255) / 256, 256, 0, stream>>>(
        ald2p, ald2, als2p, als2, hs2p, hs2f);

    // ================= fused conv2/classifier =================
    conv2_fused_kernel<<<(N_TX + 3) / 4, 256, 0, stream>>>(
        rowptr_t, rec_t, hs2f, als2, ald2, b2_u2t, Wc, bc, out, N_TX);
}

// Round 15
// 534.075 us; speedup vs baseline: 1.0985x; 1.0083x over previous
//
#include <hip/hip_runtime.h>
#include <hip/hip_bf16.h>
#include <math.h>

#define N_TX   100000
#define N_USER 50000
#define F_TX   128
#define F_USER 64
#define HID    64
#define NH     4
#define OUTC   32
#define NE     500000
#define HC1    256          // NH*HID
#define SLOPE  0.2f
#define NB_T   391          // (N_TX+255)/256
#define NB_U   196          // (N_USER+255)/256

__device__ __forceinline__ float elu_f(float x) { return x > 0.f ? x : (expf(x) - 1.f); }
// fast attention-weight exp: softmax normalizes away the ~1ulp v_exp error
__device__ __forceinline__ float lrelu_exp_fast(float x) { x = x > 0.f ? x : SLOPE * x; return __expf(x); }

// row-of-acc FMA: acc[i][0..3] += XS * WV.{x,y,z,w}  (named vars only -> register-resident)
#define ACC_STEP(i, XS, WV) \
    acc[i][0] = fmaf((XS), (WV).x, acc[i][0]); \
    acc[i][1] = fmaf((XS), (WV).y, acc[i][1]); \
    acc[i][2] = fmaf((XS), (WV).z, acc[i][2]); \
    acc[i][3] = fmaf((XS), (WV).w, acc[i][3]);
#define ACC4(i, XV) \
    ACC_STEP(i, (XV).x, w0) ACC_STEP(i, (XV).y, w1) \
    ACC_STEP(i, (XV).z, w2) ACC_STEP(i, (XV).w, w3)

// ====== DUAL projection GEMM (tx + user in one launch) with fused ELU + attn epilogue ======
// blockIdx.y < NB1 -> tx params; else user params. M==64, grid.x==1 for both.
// Pad = 68 floats (272B, 16B-aligned) -> ds_read_b128 operands, conflict-free (r10: -40us).
__global__ __launch_bounds__(256) void gemm_proj_attn_dual(
    const float* __restrict__ A1, const float* __restrict__ B1, const float* __restrict__ bias1,
    float* __restrict__ C1, int N1, int K1,
    const float* __restrict__ Ma1, float* __restrict__ oa1,
    const float* __restrict__ Mb1, float* __restrict__ ob1, int NB1,
    const float* __restrict__ A2, const float* __restrict__ B2, const float* __restrict__ bias2,
    float* __restrict__ C2, int N2, int K2,
    const float* __restrict__ Ma2, float* __restrict__ oa2,
    const float* __restrict__ Mb2, float* __restrict__ ob2)
{
    __shared__ float As[16][68];
    __shared__ float Bs[16][68];
    const int tid = threadIdx.x;
    const int tx = tid % 16, ty = tid / 16;
    const float* A; const float* B; const float* bias; float* C; int N, K;
    const float* Ma; float* oa; const float* Mb; float* ob; int row0;
    if ((int)blockIdx.y < NB1) {
        A = A1; B = B1; bias = bias1; C = C1; N = N1; K = K1;
        Ma = Ma1; oa = oa1; Mb = Mb1; ob = ob1;
        row0 = blockIdx.y * 64;
    } else {
        A = A2; B = B2; bias = bias2; C = C2; N = N2; K = K2;
        Ma = Ma2; oa = oa2; Mb = Mb2; ob = ob2;
        row0 = (blockIdx.y - NB1) * 64;
    }
    float acc[4][4] = {};
    for (int k0 = 0; k0 < K; k0 += 16) {
        #pragma unroll
        for (int i = 0; i < 4; ++i) {
            int idx = tid * 4 + i;           // 64x16 A tile
            int r = idx >> 4, kk = idx & 15;
            int gr = row0 + r;
            As[kk][r] = (gr < N) ? A[(size_t)gr * K + (k0 + kk)] : 0.f;
        }
        #pragma unroll
        for (int i = 0; i < 4; ++i) {
            int idx = tid * 4 + i;           // 16x64 B tile (M==64, no col guard)
            int kk = idx >> 6, c = idx & 63;
            Bs[kk][c] = B[(size_t)(k0 + kk) * 64 + c];
        }
        __syncthreads();
        #pragma unroll 2
        for (int kk = 0; kk < 16; ++kk) {
            const float4 av = *(const float4*)(&As[kk][ty * 4]);
            const float4 bv = *(const float4*)(&Bs[kk][tx * 4]);
            ACC_STEP(0, av.x, bv)
            ACC_STEP(1, av.y, bv)
            ACC_STEP(2, av.z, bv)
            ACC_STEP(3, av.w, bv)
        }
        __syncthreads();
    }
    // ---- epilogue: ELU + store row + fused dots against Ma/Mb ([c][4] layout) ----
    const float4 ma0 = *(const float4*)(Ma + (tx * 4 + 0) * 4);
    const float4 ma1 = *(const float4*)(Ma + (tx * 4 + 1) * 4);
    const float4 ma2 = *(const float4*)(Ma + (tx * 4 + 2) * 4);
    const float4 ma3 = *(const float4*)(Ma + (tx * 4 + 3) * 4);
    const float4 mb0 = *(const float4*)(Mb + (tx * 4 + 0) * 4);
    const float4 mb1 = *(const float4*)(Mb + (tx * 4 + 1) * 4);
    const float4 mb2 = *(const float4*)(Mb + (tx * 4 + 2) * 4);
    const float4 mb3 = *(const float4*)(Mb + (tx * 4 + 3) * 4);
    const float4 bb  = *(const float4*)(bias + tx * 4);
    #pragma unroll
    for (int i = 0; i < 4; ++i) {
        int r = row0 + ty * 4 + i;
        bool wr = (r < N);
        float v0 = acc[i][0] + bb.x; v0 = v0 > 0.f ? v0 : (expf(v0) - 1.f);
        float v1 = acc[i][1] + bb.y; v1 = v1 > 0.f ? v1 : (expf(v1) - 1.f);
        float v2 = acc[i][2] + bb.z; v2 = v2 > 0.f ? v2 : (expf(v2) - 1.f);
        float v3 = acc[i][3] + bb.w; v3 = v3 > 0.f ? v3 : (expf(v3) - 1.f);
        if (wr) *(float4*)(C + (size_t)r * 64 + tx * 4) = make_float4(v0, v1, v2, v3);
        float pax = v0 * ma0.x + v1 * ma1.x + v2 * ma2.x + v3 * ma3.x;
        float pay = v0 * ma0.y + v1 * ma1.y + v2 * ma2.y + v3 * ma3.y;
        float paz = v0 * ma0.z + v1 * ma1.z + v2 * ma2.z + v3 * ma3.z;
        float paw = v0 * ma0.w + v1 * ma1.w + v2 * ma2.w + v3 * ma3.w;
        float pbx = v0 * mb0.x + v1 * mb1.x + v2 * mb2.x + v3 * mb3.x;
        float pby = v0 * mb0.y + v1 * mb1.y + v2 * mb2.y + v3 * mb3.y;
        float pbz = v0 * mb0.z + v1 * mb1.z + v2 * mb2.z + v3 * mb3.z;
        float pbw = v0 * mb0.w + v1 * mb1.w + v2 * mb2.w + v3 * mb3.w;
        #pragma unroll
        for (int off = 1; off < 16; off <<= 1) {
            pax += __shfl_xor(pax, off); pay += __shfl_xor(pay, off);
            paz += __shfl_xor(paz, off); paw += __shfl_xor(paw, off);
            pbx += __shfl_xor(pbx, off); pby += __shfl_xor(pby, off);
            pbz += __shfl_xor(pbz, off); pbw += __shfl_xor(pbw, off);
        }
        if (tx == 0 && wr) {
            *(float4*)(oa + (size_t)r * 4) = make_float4(pax, pay, paz, paw);
            *(float4*)(ob + (size_t)r * 4) = make_float4(pbx, pby, pbz, pbw);
        }
    }
}

// ------------- fold attention vectors into weights: Mv[k,h] = sum_c W[k,h*C+c]*a[h,c] -------------
// blockIdx.x < 6: fold task; blocks 6.. zero the degree histograms (replaces hipMemsetAsync).
struct AVArgs  { const float* W; const float* a; float* out; int K; int H; int C; };
struct AVArgs6 { AVArgs t[6]; };

__global__ void attn_vecs_kernel(AVArgs6 args, int* __restrict__ degz, int nz)
{
    if (blockIdx.x >= 6) {
        int i = (blockIdx.x - 6) * 256 + threadIdx.x;
        if (i < nz) degz[i] = 0;
        return;
    }
    AVArgs A = args.t[blockIdx.x];
    int tid = threadIdx.x;
    if (tid < A.K * A.H) {
        int k = tid % A.K, h = tid / A.K;
        float s = 0.f;
        const float* wrow = A.W + (size_t)k * (A.H * A.C) + h * A.C;
        const float* arow = A.a + h * A.C;
        for (int c = 0; c < A.C; ++c) s += wrow[c] * arow[c];
        A.out[k * A.H + h] = s;
    }
}

// ================= merged CSR build (both edge types per launch) =================
__global__ __launch_bounds__(256) void hist2_kernel(const int* __restrict__ dst_t,
    const int* __restrict__ dst_u, int* __restrict__ deg_t, int* __restrict__ deg_u)
{
    int e = blockIdx.x * 256 + threadIdx.x;
    if (e < NE) atomicAdd(&deg_t[dst_t[e]], 1);
    else {
        e -= NE;
        if (e < NE) atomicAdd(&deg_u[dst_u[e]], 1);
    }
}

__global__ __launch_bounds__(256) void block_sum2_kernel(const int* __restrict__ deg_t,
    int* __restrict__ bsum_t, const int* __restrict__ deg_u, int* __restrict__ bsum_u)
{
    __shared__ int lds[256];
    int b = blockIdx.x, t = threadIdx.x;
    const int* deg; int* bsum; int Nd, lb;
    if (b < NB_T) { deg = deg_t; bsum = bsum_t; Nd = N_TX; lb = b; }
    else         { deg = deg_u; bsum = bsum_u; Nd = N_USER; lb = b - NB_T; }
    int i = lb * 256 + t;
    lds[t] = (i < Nd) ? deg[i] : 0;
    __syncthreads();
    for (int o = 128; o > 0; o >>= 1) {
        if (t < o) lds[t] += lds[t + o];
        __syncthreads();
    }
    if (t == 0) bsum[lb] = lds[0];
}

__global__ __launch_bounds__(512) void scan_bsum2_kernel(int* __restrict__ bt,
    int* __restrict__ bu)
{
    __shared__ int lds[512];
    int t = threadIdx.x;
    {
        int v = (t < NB_T) ? bt[t] : 0;
        lds[t] = v;
        __syncthreads();
        for (int o = 1; o < 512; o <<= 1) {
            int x = (t >= o) ? lds[t - o] : 0;
            __syncthreads();
            lds[t] += x;
            __syncthreads();
        }
        if (t < NB_T) bt[t] = lds[t] - v;
        __syncthreads();
    }
    {
        int v = (t < NB_U) ? bu[t] : 0;
        lds[t] = v;
        __syncthreads();
        for (int o = 1; o < 512; o <<= 1) {
            int x = (t >= o) ? lds[t - o] : 0;
            __syncthreads();
            lds[t] += x;
            __syncthreads();
        }
        if (t < NB_U) bu[t] = lds[t] - v;
    }
}

__global__ __launch_bounds__(256) void scan_final2_kernel(
    const int* __restrict__ deg_t, const int* __restrict__ be_t,
    int* __restrict__ rowptr_t, int* __restrict__ cur_t,
    const int* __restrict__ deg_u, const int* __restrict__ be_u,
    int* __restrict__ rowptr_u, int* __restrict__ cur_u)
{
    __shared__ int lds[256];
    int b = blockIdx.x, t = threadIdx.x;
    const int* deg; const int* be; int* rowptr; int* cursor; int Nd, lb;
    if (b < NB_T) { deg = deg_t; be = be_t; rowptr = rowptr_t; cursor = cur_t; Nd = N_TX; lb = b; }
    else         { deg = deg_u; be = be_u; rowptr = rowptr_u; cursor = cur_u; Nd = N_USER; lb = b - NB_T; }
    int i = lb * 256 + t;
    int v = (i < Nd) ? deg[i] : 0;
    lds[t] = v;
    __syncthreads();
    for (int o = 1; o < 256; o <<= 1) {
        int x = (t >= o) ? lds[t - o] : 0;
        __syncthreads();
        lds[t] += x;
        __syncthreads();
    }
    int excl = lds[t] - v + be[lb];
    if (i < Nd) {
        rowptr[i] = excl;
        cursor[i] = excl;
        if (i == Nd - 1) rowptr[Nd] = NE;
    }
}

// ---- scatter + edge-weight precompute into PACKED 32B records {w:float4, s:int, pad} ----
// Both 16B stores hit the SAME 64B line -> 1 random line/edge (r13: -22us vs split arrays).
__global__ __launch_bounds__(256) void scatter_ew_kernel(
    const int* __restrict__ src, const int* __restrict__ dst,
    int* __restrict__ cur, float* __restrict__ rec,
    const float* __restrict__ als, const float* __restrict__ ald)
{
    int e = blockIdx.x * 256 + threadIdx.x;
    if (e >= NE) return;
    int s = src[e], d = dst[e];
    int p = atomicAdd(&cur[d], 1);
    float4 a = *(const float4*)(als + (size_t)s * 4);
    float4 b = *(const float4*)(ald + (size_t)d * 4);
    float4 w;
    w.x = lrelu_exp_fast(a.x + b.x);
    w.y = lrelu_exp_fast(a.y + b.y);
    w.z = lrelu_exp_fast(a.z + b.z);
    w.w = lrelu_exp_fast(a.w + b.w);
    float* r8 = rec + (size_t)p * 8;
    *(float4*)(r8)     = w;
    *(float4*)(r8 + 4) = make_float4(__int_as_float(s), 0.f, 0.f, 0.f);
}

// ================= conv1 aggregation: one wave per dst node, packed records ==========
__device__ __forceinline__ void acc_edge(int i, int lane,
    const float* __restrict__ rec, const float* __restrict__ hsrc,
    float& a0, float& a1, float& a2, float& a3,
    float& w0, float& w1, float& w2, float& w3)
{
    const float* r8 = rec + (size_t)i * 8;
    float4 e = *(const float4*)(r8);                   // streaming broadcast (same line as s)
    int s = __float_as_int(r8[4]);
    float x = hsrc[(size_t)s * 64 + lane];             // 256B gather
    a0 = fmaf(e.x, x, a0); w0 += e.x;
    a1 = fmaf(e.y, x, a1); w1 += e.y;
    a2 = fmaf(e.z, x, a2); w2 += e.z;
    a3 = fmaf(e.w, x, a3); w3 += e.w;
}

__global__ __launch_bounds__(256) void agg_conv1_kernel(const int* __restrict__ rowptr,
    const float* __restrict__ rec, const float* __restrict__ hsrc,
    float* __restrict__ agg, int Nd)
{
    int d = blockIdx.x * 4 + (threadIdx.x >> 6);
    int lane = threadIdx.x & 63;
    if (d >= Nd) return;
    int beg = rowptr[d], end = rowptr[d + 1];
    float a0 = 0.f, a1 = 0.f, a2 = 0.f, a3 = 0.f;
    float w0 = 0.f, w1 = 0.f, w2 = 0.f, w3 = 0.f;
    int i = beg;
    for (; i + 2 <= end; i += 2) {
        acc_edge(i,     lane, rec, hsrc, a0, a1, a2, a3, w0, w1, w2, w3);
        acc_edge(i + 1, lane, rec, hsrc, a0, a1, a2, a3, w0, w1, w2, w3);
    }
    if (i < end)
        acc_edge(i, lane, rec, hsrc, a0, a1, a2, a3, w0, w1, w2, w3);
    float* o = agg + (size_t)d * 256;
    o[lane]       = a0 / (w0 + 1e-16f);
    o[64 + lane]  = a1 / (w1 + 1e-16f);
    o[128 + lane] = a2 / (w2 + 1e-16f);
    o[192 + lane] = a3 / (w3 + 1e-16f);
}

// ========== conv1 dst-side transform v10: v6 core + optional fused hs2 partial GEMM ========
// Core (proven 65-69us): 64-node tile per head, 4x4/thread, LDS+VALU issue-bound;
// `#pragma unroll 1` load-bearing (r1/r2 scratch-spill). launch_bounds(256,4): measured
// VGPR=52 leaves headroom to the 128-reg cap -> safe; targets the 3->4 blocks/CU gap
// (occupancy was 37% with no visible resource limit). fuse2==1 (user side): y tile parked
// in dead sX, multiplied by W2 head-slice -> hs2 partials; u1 never materialized (r14: -26us).
__global__ __launch_bounds__(256, 4) void transform_v10(
    const float* __restrict__ agg, const float* __restrict__ W1,
    const float* __restrict__ b1, const float* __restrict__ vvec,
    float* __restrict__ dot_part, const float* __restrict__ W2,
    float* __restrict__ hs2p, int Nd, int fuse2)
{
    constexpr int SXP = 68;                   // row stride (floats): 272B, 16B-aligned
    __shared__ float sX[64 * SXP];            // [node][c]; reused as y-buffer in phase 2
    __shared__ float sW[64 * 64];             // [c][col]; reused for W2 slice in phase 2
    const int tid  = threadIdx.x;
    const int w    = tid >> 6;
    const int lane = tid & 63;
    const int h    = blockIdx.y;
    const int base = blockIdx.x * 64;

    // ---- stage x tile: wave w stages node rows, 256B contiguous per row ----
    #pragma unroll
    for (int it = 0; it < 4; ++it) {
        int r  = w * 16 + it * 4 + (lane >> 4);
        int c0 = (lane & 15) * 4;
        int g  = base + r;
        float4 v = make_float4(0.f, 0.f, 0.f, 0.f);
        if (g < Nd) v = *(const float4*)(agg + (size_t)g * 256 + h * 64 + c0);
        *(float4*)(sX + r * SXP + c0) = v;
    }
    // ---- stage W head-slice: row c, cols h*64..h*64+63 ----
    #pragma unroll
    for (int it = 0; it < 4; ++it) {
        int c    = w * 16 + it * 4 + (lane >> 4);
        int col0 = (lane & 15) * 4;
        *(float4*)(sW + c * 64 + col0) =
            *(const float4*)(W1 + (size_t)c * 256 + h * 64 + col0);
    }
    __syncthreads();

    const int tx = tid & 15;                  // col group (4 cols)
    const int ty = tid >> 4;                  // node group (4 nodes)
    float acc[4][4] = {};

    #pragma unroll 1
    for (int c0 = 0; c0 < 64; c0 += 4) {
        const float4 x0 = *(const float4*)(sX + (ty * 4 + 0) * SXP + c0);
        const float4 x1 = *(const float4*)(sX + (ty * 4 + 1) * SXP + c0);
        const float4 x2 = *(const float4*)(sX + (ty * 4 + 2) * SXP + c0);
        const float4 x3 = *(const float4*)(sX + (ty * 4 + 3) * SXP + c0);
        const float4 w0 = *(const float4*)(sW + (c0 + 0) * 64 + tx * 4);
        const float4 w1 = *(const float4*)(sW + (c0 + 1) * 64 + tx * 4);
        const float4 w2 = *(const float4*)(sW + (c0 + 2) * 64 + tx * 4);
        const float4 w3 = *(const float4*)(sW + (c0 + 3) * 64 + tx * 4);
        ACC4(0, x0)
        ACC4(1, x1)
        ACC4(2, x2)
        ACC4(3, x3)
    }
    __syncthreads();   // all sX/sW reads drained before phase-2 reuse

    // ---- epilogue: bias + ELU, dot-partials; fuse2: park y in sX ----
    const float4 bb = *(const float4*)(b1   + h * 64 + tx * 4);
    const float4 vv = *(const float4*)(vvec + h * 64 + tx * 4);
    float* dp = dot_part + (size_t)h * Nd;
    #pragma unroll
    for (int i = 0; i < 4; ++i) {
        int g = base + ty * 4 + i;            // uniform across the 16-lane tx group
        float v0 = acc[i][0] + bb.x; v0 = v0 > 0.f ? v0 : (expf(v0) - 1.f);
        float v1 = acc[i][1] + bb.y; v1 = v1 > 0.f ? v1 : (expf(v1) - 1.f);
        float v2 = acc[i][2] + bb.z; v2 = v2 > 0.f ? v2 : (expf(v2) - 1.f);
        float v3 = acc[i][3] + bb.w; v3 = v3 > 0.f ? v3 : (expf(v3) - 1.f);
        if (fuse2)                            // OOB rows hold elu(bias) (finite), discarded later
            *(float4*)(sX + (ty * 4 + i) * SXP + tx * 4) = make_float4(v0, v1, v2, v3);
        float s = v0 * vv.x + v1 * vv.y + v2 * vv.z + v3 * vv.w;
        s += __shfl_xor(s, 1); s += __shfl_xor(s, 2);
        s += __shfl_xor(s, 4); s += __shfl_xor(s, 8);
        if (tx == 0 && g < Nd) dp[g] = s;
    }

    if (!fuse2) return;

    // ---- phase 2: hs2 partial = y[64x64] . W2[h*64..h*64+63][0..31] ----
    {
        int idx0 = tid * 8;                   // 2048 floats = 64 rows x 32 cols
        int r = idx0 >> 5, j0 = idx0 & 31;
        const float* wsrc = W2 + (size_t)(h * 64 + r) * 32 + j0;
        *(float4*)(sW + r * 32 + j0)     = *(const float4*)(wsrc);
        *(float4*)(sW + r * 32 + j0 + 4) = *(const float4*)(wsrc + 4);
    }
    __syncthreads();

    float a2[4][2] = {};
    #pragma unroll 1
    for (int r0 = 0; r0 < 64; r0 += 4) {
        const float4 y0 = *(const float4*)(sX + (ty * 4 + 0) * SXP + r0);
        const float4 y1 = *(const float4*)(sX + (ty * 4 + 1) * SXP + r0);
        const float4 y2 = *(const float4*)(sX + (ty * 4 + 2) * SXP + r0);
        const float4 y3 = *(const float4*)(sX + (ty * 4 + 3) * SXP + r0);
        const float2 wA = *(const float2*)(sW + (r0 + 0) * 32 + tx * 2);
        const float2 wB = *(const float2*)(sW + (r0 + 1) * 32 + tx * 2);
        const float2 wC = *(const float2*)(sW + (r0 + 2) * 32 + tx * 2);
        const float2 wD = *(const float2*)(sW + (r0 + 3) * 32 + tx * 2);
        #define P2(i, YV) \
            a2[i][0] = fmaf((YV).x, wA.x, a2[i][0]); a2[i][1] = fmaf((YV).x, wA.y, a2[i][1]); \
            a2[i][0] = fmaf((YV).y, wB.x, a2[i][0]); a2[i][1] = fmaf((YV).y, wB.y, a2[i][1]); \
            a2[i][0] = fmaf((YV).z, wC.x, a2[i][0]); a2[i][1] = fmaf((YV).z, wC.y, a2[i][1]); \
            a2[i][0] = fmaf((YV).w, wD.x, a2[i][0]); a2[i][1] = fmaf((YV).w, wD.y, a2[i][1]);
        P2(0, y0) P2(1, y1) P2(2, y2) P2(3, y3)
        #undef P2
    }
    float* hp = hs2p + (size_t)h * ((size_t)N_USER * 32);
    #pragma unroll
    for (int i = 0; i < 4; ++i) {
        int g = base + ty * 4 + i;
        if (g < Nd)
            *(float2*)(hp + (size_t)g * 32 + tx * 2) = make_float2(a2[i][0], a2[i][1]);
    }
}

// ------ combine3: ald2 = sum_h ald2p; als2 = sum_h als2p; hs2 = sum_h hs2p ------
__global__ __launch_bounds__(256) void combine3_kernel(
    const float* __restrict__ ap, float* __restrict__ o1,
    const float* __restrict__ bp, float* __restrict__ o2,
    const float* __restrict__ hp, float* __restrict__ o3)
{
    int i = blockIdx.x * 256 + threadIdx.x;
    if (i < N_TX) {
        o1[i] = ap[i] + ap[N_TX + i] + ap[2 * N_TX + i] + ap[3 * N_TX + i];
    } else if (i < N_TX + N_USER) {
        int j = i - N_TX;
        o2[j] = bp[j] + bp[N_USER + j] + bp[2 * N_USER + j] + bp[3 * N_USER + j];
    } else {
        int k = i - N_TX - N_USER;
        const int HS = N_USER * 32;
        if (k < HS)
            o3[k] = hp[k] + hp[HS + k] + hp[2 * HS + k] + hp[3 * HS + k];
    }
}

// ================= conv2: fused edge-softmax + aggregation + bias/ELU + classifier ==========
// src ids come from the packed rec_t records (csr array eliminated).
__global__ __launch_bounds__(256) void conv2_fused_kernel(const int* __restrict__ rowptr,
    const float* __restrict__ rec, const float* __restrict__ hs2,
    const float* __restrict__ als2, const float* __restrict__ ald2,
    const float* __restrict__ b2, const float* __restrict__ Wc, const float* __restrict__ bc,
    float* __restrict__ out, int Nd)
{
    int d = blockIdx.x * 4 + (threadIdx.x >> 6);
    int lane = threadIdx.x & 63;
    if (d >= Nd) return;
    int beg = rowptr[d], end = rowptr[d + 1];
    float aldd = ald2[d];
    int half = lane >> 5, c = lane & 31;
    float acc = 0.f, wsum = 0.f;
    for (int i = beg + half; i < end; i += 2) {
        int s = __float_as_int(rec[(size_t)i * 8 + 4]);
        float w = lrelu_exp_fast(als2[s] + aldd);
        acc = fmaf(w, hs2[(size_t)s * 32 + c], acc);
        wsum += w;
    }
    acc  += __shfl_down(acc, 32);
    wsum += __shfl_down(wsum, 32);
    float val = 0.f;
    if (lane < 32) {
        float t2 = acc / (wsum + 1e-16f) + b2[c];
        t2 = t2 > 0.f ? t2 : (expf(t2) - 1.f);
        val = t2 * Wc[c];
    }
    #pragma unroll
    for (int o = 16; o > 0; o >>= 1) val += __shfl_down(val, o);
    if (lane == 0) out[d] = val + bc[0];
}

extern "C" void kernel_launch(void* const* d_in, const int* in_sizes, int n_in,
                              void* d_out, int out_size, void* d_ws, size_t ws_size,
                              hipStream_t stream)
{
    const float* x_tx    = (const float*)d_in[0];
    const float* x_user  = (const float*)d_in[1];
    const int*   ei_u2t  = (const int*)d_in[2];
    const int*   ei_t2u  = (const int*)d_in[3];
    const float* Wp_tx   = (const float*)d_in[4];
    const float* bp_tx   = (const float*)d_in[5];
    const float* Wp_user = (const float*)d_in[6];
    const float* bp_user = (const float*)d_in[7];
    const float* W1_u2t  = (const float*)d_in[8];
    const float* as1_u2t = (const float*)d_in[9];
    const float* ad1_u2t = (const float*)d_in[10];
    const float* b1_u2t  = (const float*)d_in[11];
    const float* W2_u2t  = (const float*)d_in[12];
    const float* as2_u2t = (const float*)d_in[13];
    const float* ad2_u2t = (const float*)d_in[14];
    const float* b2_u2t  = (const float*)d_in[15];
    const float* W1_t2u  = (const float*)d_in[16];
    const float* as1_t2u = (const float*)d_in[17];
    const float* ad1_t2u = (const float*)d_in[18];
    const float* b1_t2u  = (const float*)d_in[19];
    const float* Wc      = (const float*)d_in[24];
    const float* bc      = (const float*)d_in[25];
    float* out = (float*)d_out;
    float* ws  = (float*)d_ws;

    const int* src_u2t = ei_u2t;            // user ids
    const int* dst_u2t = ei_u2t + NE;       // tx ids
    const int* src_t2u = ei_t2u;            // tx ids
    const int* dst_u   = ei_t2u + NE;       // user ids

    // ---- workspace layout (floats) ----
    float* h_tx   = ws;                     //  6,400,000
    float* h_us   = ws + 6400000;           //  3,200,000
    float* parts  = ws + 9600000;           //    600,000  (ald2p 4xN_TX, als2p 4xN_USER)
    float* als2   = ws + 11200000;          //     50,000
    float* ald2   = ws + 11250000;          //    100,000
    float* als_us = ws + 11350000;          //    200,000  (user src-attn for u2t)
    float* ald_us = ws + 11550000;          //    200,000  (user dst-attn for t2u)
    float* als_tx = ws + 11750000;          //    400,000  (tx src-attn for t2u)
    float* ald_tx = ws + 12150000;          //    400,000  (tx dst-attn for u2t)
    float* agg    = ws + 12550000;          // 25,600,000  (tx agg; user agg in lower 12.8M;
                                            //  dead tx zone reused: rec_u, hs2p, hs2f)
    float* avec   = ws + 38150000;          //      1,536
    float* ald2p = parts;                   //    400,000  (4 x N_TX)
    float* als2p = parts + 400000;          //    200,000  (4 x N_USER)
    float* rec_t  = ws + 38152000;          //  4,000,000  (8 x NE packed {w4,s} records, u2t)
    float* rec_u  = agg + 12800000;         //  4,000,000  (dead tx-agg zone after transform_t)
    float* hs2p   = agg + 17000000;         //  6,400,000  (4 x N_USER x 32 partials)
    float* hs2f   = agg + 23500000;         //  1,600,000  (final hs2; ends 25.1M < 25.6M)
    // ---- int region ----
    int* ibase    = (int*)(ws + 42152000);
    int* deg_t    = ibase;                  //   100,000
    int* deg_u    = ibase + 100000;         //    50,000
    int* rowptr_t = ibase + 150000;         //   100,001
    int* cur_t    = ibase + 250001;         //   100,000
    int* rowptr_u = ibase + 350001;         //    50,001
    int* cur_u    = ibase + 400002;         //    50,000
    int* bsum_t   = ibase + 450052;         //       512
    int* bsum_u   = ibase + 450564;         //       512

    float* Msrc_u2t = avec + 0;
    float* Mdst_u2t = avec + 256;
    float* Msrc_t2u = avec + 512;
    float* Mdst_t2u = avec + 768;
    float* vsrc2    = avec + 1024;          // fold(W2, as2): als2 = u1 . vsrc2
    float* vdst2    = avec + 1280;          // fold(W2, ad2): ald2 = t1 . vdst2

    // ---- fold attention vectors into weights + zero degree histograms (one launch) ----
    AVArgs6 av;
    av.t[0] = { W1_u2t, as1_u2t, Msrc_u2t, HID, NH, HID };
    av.t[1] = { W1_u2t, ad1_u2t, Mdst_u2t, HID, NH, HID };
    av.t[2] = { W1_t2u, as1_t2u, Msrc_t2u, HID, NH, HID };
    av.t[3] = { W1_t2u, ad1_t2u, Mdst_t2u, HID, NH, HID };
    av.t[4] = { W2_u2t, as2_u2t, vsrc2, HC1, 1, OUTC };
    av.t[5] = { W2_u2t, ad2_u2t, vdst2, HC1, 1, OUTC };
    attn_vecs_kernel<<<6 + (150000 + 255) / 256, 256, 0, stream>>>(av, deg_t, 150000);

    // ---- CSR histogram + prefix scans (no scatter yet) ----
    hist2_kernel<<<(2 * NE + 255) / 256, 256, 0, stream>>>(dst_u2t, dst_u, deg_t, deg_u);
    block_sum2_kernel<<<NB_T + NB_U, 256, 0, stream>>>(deg_t, bsum_t, deg_u, bsum_u);
    scan_bsum2_kernel<<<1, 512, 0, stream>>>(bsum_t, bsum_u);
    scan_final2_kernel<<<NB_T + NB_U, 256, 0, stream>>>(
        deg_t, bsum_t, rowptr_t, cur_t, deg_u, bsum_u, rowptr_u, cur_u);

    // ---- input projections (both node types, ONE launch) with fused attn epilogue ----
    const int NB1 = (N_TX + 63) / 64;
    const int NB2 = (N_USER + 63) / 64;
    gemm_proj_attn_dual<<<dim3(1, NB1 + NB2), 256, 0, stream>>>(
        x_tx, Wp_tx, bp_tx, h_tx, N_TX, F_TX,
        Mdst_u2t, ald_tx, Msrc_t2u, als_tx, NB1,
        x_user, Wp_user, bp_user, h_us, N_USER, F_USER,
        Msrc_u2t, als_us, Mdst_t2u, ald_us);

    // ================= conv1, u2t (dst = tx): scatter -> agg -> transform ==========
    scatter_ew_kernel<<<(NE + 255) / 256, 256, 0, stream>>>(
        src_u2t, dst_u2t, cur_t, rec_t, als_us, ald_tx);
    agg_conv1_kernel<<<(N_TX + 3) / 4, 256, 0, stream>>>(
        rowptr_t, rec_t, h_us, agg, N_TX);
    transform_v10<<<dim3((N_TX + 63) / 64, NH), 256, 0, stream>>>(
        agg, W1_u2t, b1_u2t, vdst2, ald2p, nullptr, nullptr, N_TX, 0);

    // ================= conv1, t2u (dst = user): scatter (rec_u in dead tx-agg zone)
    //     -> agg (lower 12.8M) -> transform + fused hs2 partials (u1 never written) ==========
    scatter_ew_kernel<<<(NE + 255) / 256, 256, 0, stream>>>(
        src_t2u, dst_u, cur_u, rec_u, als_tx, ald_us);
    agg_conv1_kernel<<<(N_USER + 3) / 4, 256, 0, stream>>>(
        rowptr_u, rec_u, h_tx, agg, N_USER);
    transform_v10<<<dim3((N_USER + 63) / 64, NH), 256, 0, stream>>>(
        agg, W1_t2u, b1_t2u, vsrc2, als2p, W2_u2t, hs2p, N_USER, 1);

    // ---- combine head partials (ald2, als2, hs2) ----
    combine3_kernel<<<(N_TX + N_USER + N_USER * 32 + 255) / 256, 256, 0, stream>>>(
        ald2p, ald2, als2p, als2, hs2p, hs2f);

    // ================= fused conv2/classifier =================
    conv2_fused_kernel<<<(N_TX + 3) / 4, 256, 0, stream>>>(
        rowptr_t, rec_t, hs2f, als2, ald2, b2_u2t, Wc, bc, out, N_TX);
}